// Round 9
// baseline (493.265 us; speedup 1.0000x reference)
//
#include <hip/hip_runtime.h>
#include <hip/hip_cooperative_groups.h>

namespace cg = cooperative_groups;

// GCN forward: cooperative fused CSR build + gather aggregation.
// Lessons ledger:
//   R4/R9:  atomic float aggregation (global) loses 5-10x to register gather.
//   R15:    ...and LDS float atomics lose too (591us). Register accum only.
//   R17:    scattered 4B global writes forbidden (15x partial-line write
//           amplification across 8 non-coherent L2s -> 300us scatter).
//   R13/18/20: gather is random-line-fetch bound; x8 batches + index prefetch
//           got aggF to 45us @ 2.6TB/s. Near floor.
//   R22:    top-5 owned by harness 256MiB/41.5us workspace fill (untouchable
//           fixed cost); ~4us marginal cost per dispatch (R6->R7 experiment).
//   R23 (this round): R8's coop build at 280us was self-inflicted: the
//           __launch_bounds__(512,4) clamp reported VGPR=32 and spilled the
//           register-staging arrays (~25MB excess WRITE == spill arithmetic;
//           VALUBusy 2.3% == pure stall). Fix: plain bounds, NO register
//           staging (R5 proved it null anyway), CHUNK=6400 -> 500 chunks,
//           one chunk per block (no grid-stride, no 2:1 sync imbalance).
// Pipeline (5 dispatches):
//   memset(bcur)
//   build (cooperative, 512x512): phase A = radix partition, one chunk/block;
//     grid.sync; phase B = inline bucket-base wave-scan + per-bucket
//     hist/scan -> counts/offs/dinv + CSR placement.
//   gemm1: xwd = (x@W1)*dinv, bf16 64B rows, 4 thr/node x 2 nodes/thr.
//   aggF: layer-1 gather (4 lanes/node, x8 pipelined) + fused gemm2 -> h2wd.
//   aggS16f: layer-2 gather (2 lanes/node, x8 pipelined) + fused head -> out.

#define TPB 256
#define NBUCK 512
#define BCAP 8192    // bucket capacity; mean ~6272, sd ~79 -> 24 sigma margin
#define CHUNK 6400   // edges per phase-A block; ceil(3.2M/6400)=500 <= 512

__device__ __forceinline__ unsigned f2bf(float f) {  // RNE fp32->bf16
    unsigned u = __float_as_uint(f);
    return (u + 0x7FFFu + ((u >> 16) & 1u)) >> 16;
}
__device__ __forceinline__ float bflo(unsigned u) { return __uint_as_float(u << 16); }
__device__ __forceinline__ float bfhi(unsigned u) { return __uint_as_float(u & 0xFFFF0000u); }

// Exclusive scan over 512 values (one per thread) using wave shfl scans.
__device__ __forceinline__ int excl_scan_512(int v, int* wsum, int tid) {
    int lane = tid & 63, wv = tid >> 6;
    int x = v;
#pragma unroll
    for (int d = 1; d < 64; d <<= 1) {
        int y = __shfl_up(x, d, 64);
        if (lane >= d) x += y;
    }
    if (lane == 63) wsum[wv] = x;          // inclusive wave sum
    __syncthreads();
    if (tid < 64) {
        int s = (lane < 8) ? wsum[lane] : 0;
#pragma unroll
        for (int d = 1; d < 8; d <<= 1) {
            int y = __shfl_up(s, d, 64);
            if (lane >= d) s += y;
        }
        if (lane < 8) wsum[lane] = s;      // inclusive across waves
    }
    __syncthreads();
    int base = (wv > 0) ? wsum[wv - 1] : 0;
    return base + x - v;                   // exclusive prefix
}

// Cooperative fused build. Phase A: radix partition (one chunk per block,
// plain strided loops, NO register staging -> no spill). grid.sync.
// Phase B: inline bbase scan + per-bucket hist/scan -> CSR.
// LDS 46.6KB -> 3 blocks/CU; VGPR ~48 -> coop residency (2/CU) guaranteed.
__global__ __launch_bounds__(512) void build_kernel(
        const int* __restrict__ src, const int* __restrict__ dst,
        int* __restrict__ bcur, unsigned* __restrict__ staging,
        int* __restrict__ offs, int* __restrict__ counts,
        float* __restrict__ dinv, int* __restrict__ csr_src,
        int E, int N, int NPB, int nchunks) {
    cg::grid_group grid = cg::this_grid();
    __shared__ unsigned packed[CHUNK];         // 25.6 KB
    __shared__ unsigned short buckb[CHUNK];    // 12.8 KB
    __shared__ int hist[NBUCK];                // 2 KB each
    __shared__ int lcur[NBUCK];
    __shared__ int lstart[NBUCK];
    __shared__ int gbase[NBUCK];
    __shared__ int wsum[8];
    int tid = threadIdx.x;

    // ---- Phase A: one chunk per block ----
    if (blockIdx.x < nchunks) {
        int start = blockIdx.x * CHUNK;
        int sz = min(CHUNK, E - start);
        hist[tid] = 0;
        __syncthreads();
        for (int i = tid; i < sz; i += 512)
            atomicAdd(&hist[(unsigned)dst[start + i] / (unsigned)NPB], 1);
        __syncthreads();
        int v = hist[tid];
        int excl = excl_scan_512(v, wsum, tid);
        lstart[tid] = excl;
        lcur[tid] = 0;
        gbase[tid] = atomicAdd(&bcur[tid], v); // one reservation per (block,bucket)
        __syncthreads();
        for (int i = tid; i < sz; i += 512) {  // re-read dst/src (L2-hot)
            unsigned d = (unsigned)dst[start + i];
            unsigned s = (unsigned)src[start + i];
            unsigned b = d / (unsigned)NPB;
            unsigned loc = d - b * (unsigned)NPB;
            int pos = atomicAdd(&lcur[b], 1);
            int si = lstart[b] + pos;
            packed[si] = (loc << 20) | s;      // loc<=195 (12b), src<2^17
            buckb[si] = (unsigned short)b;
        }
        __syncthreads();
        for (int i = tid; i < sz; i += 512) {  // bucket-contiguous bulk write
            unsigned b = buckb[i];
            int dsti = gbase[b] + (i - lstart[b]);
            if (dsti < BCAP)
                staging[(size_t)b * BCAP + dsti] = packed[i];
        }
    }

    __threadfence();                           // release staging + bcur
    grid.sync();
    __threadfence();                           // acquire

    // ---- Phase B: bucket b = blockIdx.x ----
    int b = blockIdx.x;
    int myv = min(bcur[tid], BCAP);
    int excl = excl_scan_512(myv, wsum, tid);  // inline bbase (2 barriers)
    gbase[tid] = excl;
    hist[tid] = 0;
    __syncthreads();
    int base = gbase[b];
    int sz = min(bcur[b], BCAP);
    int n0 = b * NPB;
    int nn = min(NPB, N - n0);
    const unsigned* se = staging + (size_t)b * BCAP;

    for (int i = tid; i < sz; i += 512)
        atomicAdd(&hist[se[i] >> 20], 1);
    __syncthreads();
    int h = hist[tid];
    int excl2 = excl_scan_512(h, wsum, tid);
    lcur[tid] = excl2;
    if (tid < nn) {
        int node = n0 + tid;
        offs[node] = base + excl2;
        counts[node] = h;
        dinv[node] = rsqrtf((float)(h + 1));   // +1 self-loop
    }
    __syncthreads();
    for (int i = tid; i < sz; i += 512) {      // re-read staging (L2-warm)
        unsigned p = se[i];
        int pos = atomicAdd(&lcur[p >> 20], 1);
        csr_src[base + pos] = (int)(p & 0xFFFFFu);
    }
}

// xwd(bf16) = (x @ W1) * dinv[node].  4 threads/node x 8 cols x 2 nodes/thr.
__global__ __launch_bounds__(256) void gemm1_kernel(
        const float* __restrict__ x, const float* __restrict__ W1,
        const float* __restrict__ dinv, unsigned* __restrict__ xwd, int N) {
    __shared__ float ws_[128 * 32];
    for (int i = threadIdx.x; i < 128 * 32; i += 256) ws_[i] = W1[i];
    __syncthreads();
    int t = threadIdx.x;
    int jq = (t & 3) * 8;  // 8 output cols
    int n0 = blockIdx.x * 128 + (t >> 2) * 2;
    if (n0 >= N) return;
    int nc0 = min(n0 + 0, N - 1);
    int nc1 = min(n0 + 1, N - 1);
    const float4* xr0 = (const float4*)(x + (size_t)nc0 * 128);
    const float4* xr1 = (const float4*)(x + (size_t)nc1 * 128);
    float acc[2][8];
#pragma unroll
    for (int n = 0; n < 2; ++n)
#pragma unroll
        for (int j = 0; j < 8; ++j) acc[n][j] = 0.0f;
#pragma unroll 2
    for (int k4 = 0; k4 < 32; ++k4) {
        const float* wb = ws_ + (k4 * 4) * 32 + jq;
        float4 a0 = *(const float4*)(wb);
        float4 a1 = *(const float4*)(wb + 4);
        float4 b0 = *(const float4*)(wb + 32);
        float4 b1v = *(const float4*)(wb + 36);
        float4 c0 = *(const float4*)(wb + 64);
        float4 c1 = *(const float4*)(wb + 68);
        float4 d0 = *(const float4*)(wb + 96);
        float4 d1 = *(const float4*)(wb + 100);
        float4 xv0 = xr0[k4];
        float4 xv1 = xr1[k4];
#pragma unroll
        for (int n = 0; n < 2; ++n) {
            float4 xv = (n == 0) ? xv0 : xv1;
            acc[n][0] += xv.x * a0.x + xv.y * b0.x + xv.z * c0.x + xv.w * d0.x;
            acc[n][1] += xv.x * a0.y + xv.y * b0.y + xv.z * c0.y + xv.w * d0.y;
            acc[n][2] += xv.x * a0.z + xv.y * b0.z + xv.z * c0.z + xv.w * d0.z;
            acc[n][3] += xv.x * a0.w + xv.y * b0.w + xv.z * c0.w + xv.w * d0.w;
            acc[n][4] += xv.x * a1.x + xv.y * b1v.x + xv.z * c1.x + xv.w * d1.x;
            acc[n][5] += xv.x * a1.y + xv.y * b1v.y + xv.z * c1.y + xv.w * d1.y;
            acc[n][6] += xv.x * a1.z + xv.y * b1v.z + xv.z * c1.z + xv.w * d1.z;
            acc[n][7] += xv.x * a1.w + xv.y * b1v.w + xv.z * c1.w + xv.w * d1.w;
        }
    }
#pragma unroll
    for (int n = 0; n < 2; ++n) {
        int node = n0 + n;
        if (node >= N) break;
        float d = dinv[node];
        unsigned pk0 = f2bf(acc[n][0] * d) | (f2bf(acc[n][1] * d) << 16);
        unsigned pk1 = f2bf(acc[n][2] * d) | (f2bf(acc[n][3] * d) << 16);
        unsigned pk2 = f2bf(acc[n][4] * d) | (f2bf(acc[n][5] * d) << 16);
        unsigned pk3 = f2bf(acc[n][6] * d) | (f2bf(acc[n][7] * d) << 16);
        ((uint4*)(xwd + (size_t)node * 16))[t & 3] = make_uint4(pk0, pk1, pk2, pk3);
    }
}

// Layer-1 aggregate FUSED with gemm2: 4 lanes/node, x8 gather batches with
// next-batch index prefetch, register accum, then
// h2wd = (relu(agg*dv + b1) @ W2) * dv via LDS W2 + 12-shuffle butterfly.
__global__ __launch_bounds__(256) void aggF_kernel(
        const int* __restrict__ offs, const int* __restrict__ counts,
        const int* __restrict__ csr_src, const float* __restrict__ dinv,
        const unsigned* __restrict__ xwd, const float* __restrict__ b1,
        const float* __restrict__ W2, unsigned* __restrict__ h2wd, int N) {
    __shared__ float ws2[32 * 16];
    for (int i = threadIdx.x; i < 512; i += 256) ws2[i] = W2[i];
    __syncthreads();
    int t = threadIdx.x;
    int q = t & 3;                       // 16B slice
    int node = blockIdx.x * 64 + (t >> 2);
    if (node >= N) return;
    int off = offs[node];
    int deg = counts[node];
    float acc[8];
    {
        uint4 v = ((const uint4*)(xwd + (size_t)node * 16))[q];  // self term
        acc[0] = bflo(v.x); acc[1] = bfhi(v.x);
        acc[2] = bflo(v.y); acc[3] = bfhi(v.y);
        acc[4] = bflo(v.z); acc[5] = bfhi(v.z);
        acc[6] = bflo(v.w); acc[7] = bfhi(v.w);
    }
    int deg8 = deg & ~7;
    int idx[8];
    if (deg8 > 0) {
#pragma unroll
        for (int c = 0; c < 8; ++c) idx[c] = csr_src[off + c];
    }
    int i = 0;
    while (i < deg8) {
        uint4 v0 = ((const uint4*)(xwd + (size_t)idx[0] * 16))[q];
        uint4 v1 = ((const uint4*)(xwd + (size_t)idx[1] * 16))[q];
        uint4 v2 = ((const uint4*)(xwd + (size_t)idx[2] * 16))[q];
        uint4 v3 = ((const uint4*)(xwd + (size_t)idx[3] * 16))[q];
        uint4 v4 = ((const uint4*)(xwd + (size_t)idx[4] * 16))[q];
        uint4 v5 = ((const uint4*)(xwd + (size_t)idx[5] * 16))[q];
        uint4 v6 = ((const uint4*)(xwd + (size_t)idx[6] * 16))[q];
        uint4 v7 = ((const uint4*)(xwd + (size_t)idx[7] * 16))[q];
        i += 8;
        if (i < deg8) {                  // prefetch next batch's indices
#pragma unroll
            for (int c = 0; c < 8; ++c) idx[c] = csr_src[off + i + c];
        }
        acc[0] += ((bflo(v0.x) + bflo(v1.x)) + (bflo(v2.x) + bflo(v3.x)))
                + ((bflo(v4.x) + bflo(v5.x)) + (bflo(v6.x) + bflo(v7.x)));
        acc[1] += ((bfhi(v0.x) + bfhi(v1.x)) + (bfhi(v2.x) + bfhi(v3.x)))
                + ((bfhi(v4.x) + bfhi(v5.x)) + (bfhi(v6.x) + bfhi(v7.x)));
        acc[2] += ((bflo(v0.y) + bflo(v1.y)) + (bflo(v2.y) + bflo(v3.y)))
                + ((bflo(v4.y) + bflo(v5.y)) + (bflo(v6.y) + bflo(v7.y)));
        acc[3] += ((bfhi(v0.y) + bfhi(v1.y)) + (bfhi(v2.y) + bfhi(v3.y)))
                + ((bfhi(v4.y) + bfhi(v5.y)) + (bfhi(v6.y) + bfhi(v7.y)));
        acc[4] += ((bflo(v0.z) + bflo(v1.z)) + (bflo(v2.z) + bflo(v3.z)))
                + ((bflo(v4.z) + bflo(v5.z)) + (bflo(v6.z) + bflo(v7.z)));
        acc[5] += ((bfhi(v0.z) + bfhi(v1.z)) + (bfhi(v2.z) + bfhi(v3.z)))
                + ((bfhi(v4.z) + bfhi(v5.z)) + (bfhi(v6.z) + bfhi(v7.z)));
        acc[6] += ((bflo(v0.w) + bflo(v1.w)) + (bflo(v2.w) + bflo(v3.w)))
                + ((bflo(v4.w) + bflo(v5.w)) + (bflo(v6.w) + bflo(v7.w)));
        acc[7] += ((bfhi(v0.w) + bfhi(v1.w)) + (bfhi(v2.w) + bfhi(v3.w)))
                + ((bfhi(v4.w) + bfhi(v5.w)) + (bfhi(v6.w) + bfhi(v7.w)));
    }
    for (; i < deg; ++i) {
        int s = csr_src[off + i];
        uint4 v = ((const uint4*)(xwd + (size_t)s * 16))[q];
        acc[0] += bflo(v.x); acc[1] += bfhi(v.x);
        acc[2] += bflo(v.y); acc[3] += bfhi(v.y);
        acc[4] += bflo(v.z); acc[5] += bfhi(v.z);
        acc[6] += bflo(v.w); acc[7] += bfhi(v.w);
    }
    float dv = dinv[node];
    // fused gemm2: lane q owns k = q*8..q*8+7 of the 32-dim hidden vector
    float part[16];
#pragma unroll
    for (int j = 0; j < 16; ++j) part[j] = 0.0f;
    const float* bq = b1 + q * 8;
#pragma unroll
    for (int k = 0; k < 8; ++k) {
        float h = fmaxf(acc[k] * dv + bq[k], 0.0f);
        const float* wr = ws2 + (q * 8 + k) * 16;
        float4 w0 = *(const float4*)(wr);
        float4 w1 = *(const float4*)(wr + 4);
        float4 w2 = *(const float4*)(wr + 8);
        float4 w3 = *(const float4*)(wr + 12);
        part[0]  += h * w0.x; part[1]  += h * w0.y; part[2]  += h * w0.z; part[3]  += h * w0.w;
        part[4]  += h * w1.x; part[5]  += h * w1.y; part[6]  += h * w1.z; part[7]  += h * w1.w;
        part[8]  += h * w2.x; part[9]  += h * w2.y; part[10] += h * w2.z; part[11] += h * w2.w;
        part[12] += h * w3.x; part[13] += h * w3.y; part[14] += h * w3.z; part[15] += h * w3.w;
    }
    // half-exchange butterfly over the quad: 8 + 4 shfl total.
    float p8[8];
#pragma unroll
    for (int j = 0; j < 8; ++j) {
        float send = (q & 1) ? part[j] : part[j + 8];
        float keep = (q & 1) ? part[j + 8] : part[j];
        p8[j] = keep + __shfl_xor(send, 1, 64);
    }
    float p4[4];
#pragma unroll
    for (int j = 0; j < 4; ++j) {
        float send = (q & 2) ? p8[j] : p8[j + 4];
        float keep = (q & 2) ? p8[j + 4] : p8[j];
        p4[j] = keep + __shfl_xor(send, 2, 64);
    }
    unsigned pk0 = f2bf(p4[0] * dv) | (f2bf(p4[1] * dv) << 16);
    unsigned pk1 = f2bf(p4[2] * dv) | (f2bf(p4[3] * dv) << 16);
    int slot = ((q & 1) << 1) | ((q >> 1) & 1);   // col base /4: q0->0 q1->2 q2->1 q3->3
    ((uint2*)(h2wd + (size_t)node * 8))[slot] = make_uint2(pk0, pk1);
}

// Layer-2 aggregate + fused head, 2 lanes/node, x8 pipelined gather batches.
__global__ __launch_bounds__(256) void aggS16f_kernel(
        const int* __restrict__ offs, const int* __restrict__ counts,
        const int* __restrict__ csr_src, const float* __restrict__ dinv,
        const unsigned* __restrict__ h2wd,
        const float* __restrict__ b2, const float* __restrict__ Wf,
        const float* __restrict__ bf, float* __restrict__ out, int N) {
    __shared__ float bs_[16];
    __shared__ float wf_[16];
    __shared__ float bfv;
    int t = threadIdx.x;
    if (t < 16) { bs_[t] = b2[t]; wf_[t] = Wf[t]; }
    if (t == 0) bfv = bf[0];
    __syncthreads();
    int q = t & 1;                        // 16B slice (8 feats)
    int node = blockIdx.x * 128 + (t >> 1);
    if (node >= N) return;
    int off = offs[node];
    int deg = counts[node];
    float acc[8];
    {
        uint4 v = ((const uint4*)(h2wd + (size_t)node * 8))[q];  // self term
        acc[0] = bflo(v.x); acc[1] = bfhi(v.x);
        acc[2] = bflo(v.y); acc[3] = bfhi(v.y);
        acc[4] = bflo(v.z); acc[5] = bfhi(v.z);
        acc[6] = bflo(v.w); acc[7] = bfhi(v.w);
    }
    int deg8 = deg & ~7;
    int idx[8];
    if (deg8 > 0) {
#pragma unroll
        for (int c = 0; c < 8; ++c) idx[c] = csr_src[off + c];
    }
    int i = 0;
    while (i < deg8) {
        uint4 v0 = ((const uint4*)(h2wd + (size_t)idx[0] * 8))[q];
        uint4 v1 = ((const uint4*)(h2wd + (size_t)idx[1] * 8))[q];
        uint4 v2 = ((const uint4*)(h2wd + (size_t)idx[2] * 8))[q];
        uint4 v3 = ((const uint4*)(h2wd + (size_t)idx[3] * 8))[q];
        uint4 v4 = ((const uint4*)(h2wd + (size_t)idx[4] * 8))[q];
        uint4 v5 = ((const uint4*)(h2wd + (size_t)idx[5] * 8))[q];
        uint4 v6 = ((const uint4*)(h2wd + (size_t)idx[6] * 8))[q];
        uint4 v7 = ((const uint4*)(h2wd + (size_t)idx[7] * 8))[q];
        i += 8;
        if (i < deg8) {
#pragma unroll
            for (int c = 0; c < 8; ++c) idx[c] = csr_src[off + i + c];
        }
        acc[0] += ((bflo(v0.x) + bflo(v1.x)) + (bflo(v2.x) + bflo(v3.x)))
                + ((bflo(v4.x) + bflo(v5.x)) + (bflo(v6.x) + bflo(v7.x)));
        acc[1] += ((bfhi(v0.x) + bfhi(v1.x)) + (bfhi(v2.x) + bfhi(v3.x)))
                + ((bfhi(v4.x) + bfhi(v5.x)) + (bfhi(v6.x) + bfhi(v7.x)));
        acc[2] += ((bflo(v0.y) + bflo(v1.y)) + (bflo(v2.y) + bflo(v3.y)))
                + ((bflo(v4.y) + bflo(v5.y)) + (bflo(v6.y) + bflo(v7.y)));
        acc[3] += ((bfhi(v0.y) + bfhi(v1.y)) + (bfhi(v2.y) + bfhi(v3.y)))
                + ((bfhi(v4.y) + bfhi(v5.y)) + (bfhi(v6.y) + bfhi(v7.y)));
        acc[4] += ((bflo(v0.z) + bflo(v1.z)) + (bflo(v2.z) + bflo(v3.z)))
                + ((bflo(v4.z) + bflo(v5.z)) + (bflo(v6.z) + bflo(v7.z)));
        acc[5] += ((bfhi(v0.z) + bfhi(v1.z)) + (bfhi(v2.z) + bfhi(v3.z)))
                + ((bfhi(v4.z) + bfhi(v5.z)) + (bfhi(v6.z) + bfhi(v7.z)));
        acc[6] += ((bflo(v0.w) + bflo(v1.w)) + (bflo(v2.w) + bflo(v3.w)))
                + ((bflo(v4.w) + bflo(v5.w)) + (bflo(v6.w) + bflo(v7.w)));
        acc[7] += ((bfhi(v0.w) + bfhi(v1.w)) + (bfhi(v2.w) + bfhi(v3.w)))
                + ((bfhi(v4.w) + bfhi(v5.w)) + (bfhi(v6.w) + bfhi(v7.w)));
    }
    for (; i < deg; ++i) {
        int s = csr_src[off + i];
        uint4 v = ((const uint4*)(h2wd + (size_t)s * 8))[q];
        acc[0] += bflo(v.x); acc[1] += bfhi(v.x);
        acc[2] += bflo(v.y); acc[3] += bfhi(v.y);
        acc[4] += bflo(v.z); acc[5] += bfhi(v.z);
        acc[6] += bflo(v.w); acc[7] += bfhi(v.w);
    }
    // fused head: out[node] = relu(acc*dv + b2) . Wf + bf  (pair-split dot)
    float dv = dinv[node];
    const float* bq = bs_ + q * 8;
    const float* wq = wf_ + q * 8;
    float part = 0.f;
#pragma unroll
    for (int k = 0; k < 8; ++k)
        part += fmaxf(acc[k] * dv + bq[k], 0.f) * wq[k];
    part += __shfl_xor(part, 1, 64);  // combine the pair's halves
    if (q == 0) out[node] = part + bfv;
}

extern "C" void kernel_launch(void* const* d_in, const int* in_sizes, int n_in,
                              void* d_out, int out_size, void* d_ws, size_t ws_size,
                              hipStream_t stream) {
    const float* x  = (const float*)d_in[0];
    const int*   ei = (const int*)d_in[1];
    const float* W1 = (const float*)d_in[2];
    const float* b1 = (const float*)d_in[3];
    const float* W2 = (const float*)d_in[4];
    const float* b2 = (const float*)d_in[5];
    const float* Wf = (const float*)d_in[6];
    const float* bf = (const float*)d_in[7];

    int N = in_sizes[0] / 128;
    int E = in_sizes[1] / 2;
    const int* src = ei;       // edge_index[0]
    const int* dst = ei + E;   // edge_index[1]
    int NPB = (N + NBUCK - 1) / NBUCK;  // 196 for N=100k

    // Workspace layout
    size_t Np = ((size_t)N + 3) & ~(size_t)3;
    size_t Ep = ((size_t)E + 3) & ~(size_t)3;
    int* wsI      = (int*)d_ws;
    int* counts   = wsI;                 // Np
    int* offs     = counts + Np;         // Np
    int* bcur     = offs + Np;           // NBUCK
    int* csr_src  = bcur + NBUCK;        // Ep
    float* dinv   = (float*)(csr_src + Ep);      // Np
    unsigned* xwd = (unsigned*)(dinv + Np);      // 16*Np u32 (bf16, 64B rows)
    unsigned* staging = xwd + 16 * Np;           // NBUCK*BCAP u32 = 16.8 MB
    // h2wd (8*N u32 = 3.2 MB) aliases staging: staging written by build phase
    // A, read last by phase B; h2wd first written by aggF (later). No overlap.
    unsigned* h2wd = staging;
    float* out    = (float*)d_out;

    int nchunks = (E + CHUNK - 1) / CHUNK;   // 500 <= NBUCK
    int nbG1 = (N + 127) / 128;              // 782 (2 nodes/thread)
    int nbA32 = (N + 63) / 64;   // 64 nodes/block (4 lanes/node)
    int nbA16 = (N + 127) / 128; // 128 nodes/block (2 lanes/node)

    hipMemsetAsync(bcur, 0, NBUCK * sizeof(int), stream);
    void* cargs[] = {(void*)&src, (void*)&dst, (void*)&bcur, (void*)&staging,
                     (void*)&offs, (void*)&counts, (void*)&dinv, (void*)&csr_src,
                     (void*)&E, (void*)&N, (void*)&NPB, (void*)&nchunks};
    hipLaunchCooperativeKernel((void*)build_kernel, dim3(NBUCK), dim3(512),
                               cargs, 0, stream);
    gemm1_kernel<<<nbG1, 256, 0, stream>>>(x, W1, dinv, xwd, N);
    aggF_kernel<<<nbA32, 256, 0, stream>>>(offs, counts, csr_src, dinv, xwd,
                                           b1, W2, h2wd, N);
    aggS16f_kernel<<<nbA16, 256, 0, stream>>>(offs, counts, csr_src, dinv, h2wd,
                                              b2, Wf, bf, out, N);
}

// Round 10
// 305.707 us; speedup vs baseline: 1.6135x; 1.6135x over previous
//
#include <hip/hip_runtime.h>

// GCN forward via two-level CSR build + gather aggregation.
// Lessons ledger:
//   R4/R9:  atomic float aggregation (global) loses 5-10x to register gather.
//   R15:    ...and LDS float atomics lose too (591us). Register accum only.
//   R17:    scattered 4B global writes forbidden (15x partial-line write
//           amplification across 8 non-coherent L2s -> 300us scatter).
//   R13/18/20: gather is random-line-fetch bound; x8 batches + index prefetch
//           got aggF to 45us @ 2.6TB/s. Near floor.
//   R19:    blind micro-opts on never-profiled kernels were null 3x.
//   R22:    top-5 visibility threshold = the 41.5us harness 256MiB fill;
//           ~4us marginal cost per dispatch (R6->R7 experiment).
//   R23/24: cooperative fused build is intrinsically ~270us regardless of
//           internal structure (two different phase-A impls, same result;
//           VALUBusy 2.3%, 220GB/s). Coop abandoned per pre-commitment.
//   R25 (this round): MEASUREMENT. R6-exact structure, but binA2/buildB/
//           gemm1/aggS16f bodies run 2x internally (idempotent reps; binA2
//           reuses rep-0 gbase and skips the bcur atomic on rep 1) so each
//           crosses the 41.5us visibility threshold and surfaces in top-5
//           WITH counters. aggF stays single as the 45us reference.
//           Throwaway-speed round; reps removed next round.
// Pipeline:
//   binA2 (x2 rep): per-block LDS radix partition -> 512 dst-range buckets.
//   bbase: one-block exclusive scan of bucket sizes.
//   buildB (x2 rep): per-bucket hist+scan -> counts/offs/dinv + CSR.
//   gemm1 (x2 rep): xwd = (x@W1)*dinv, bf16 64B rows.
//   aggF: layer-1 gather (4 lanes/node, x8 pipelined) + fused gemm2 -> h2wd.
//   aggS16f (x2 rep): layer-2 gather (2 lanes/node, x8 pipelined) + head.

#define TPB 256
#define NBUCK 512
#define BCAP 8192    // bucket capacity; mean ~6272, sd ~79 -> 24 sigma margin
#define CHUNK 4096   // edges per binA2 block -> 782 blocks

__device__ __forceinline__ unsigned f2bf(float f) {  // RNE fp32->bf16
    unsigned u = __float_as_uint(f);
    return (u + 0x7FFFu + ((u >> 16) & 1u)) >> 16;
}
__device__ __forceinline__ float bflo(unsigned u) { return __uint_as_float(u << 16); }
__device__ __forceinline__ float bfhi(unsigned u) { return __uint_as_float(u & 0xFFFF0000u); }

// Exclusive scan over 512 values (one per thread) using wave shfl scans.
__device__ __forceinline__ int excl_scan_512(int v, int* wsum, int tid) {
    int lane = tid & 63, wv = tid >> 6;
    int x = v;
#pragma unroll
    for (int d = 1; d < 64; d <<= 1) {
        int y = __shfl_up(x, d, 64);
        if (lane >= d) x += y;
    }
    if (lane == 63) wsum[wv] = x;          // inclusive wave sum
    __syncthreads();
    if (tid < 64) {
        int s = (lane < 8) ? wsum[lane] : 0;
#pragma unroll
        for (int d = 1; d < 8; d <<= 1) {
            int y = __shfl_up(s, d, 64);
            if (lane >= d) s += y;
        }
        if (lane < 8) wsum[lane] = s;      // inclusive across waves
    }
    __syncthreads();
    int base = (wv > 0) ? wsum[wv - 1] : 0;
    return base + x - v;                   // exclusive prefix
}

// Phase A: block-local radix partition, bulk append to global staging.
// R25: body x2 (rep 1 reuses gbase, skips bcur atomic) for visibility.
__global__ __launch_bounds__(512) void binA2_kernel(
        const int* __restrict__ src, const int* __restrict__ dst,
        int* __restrict__ bcur, unsigned* __restrict__ staging, int E, int NPB) {
    __shared__ unsigned packed[CHUNK];         // 16 KB
    __shared__ unsigned short buckb[CHUNK];    // 8 KB
    __shared__ int hist[NBUCK];                // 2 KB each
    __shared__ int lstart[NBUCK];
    __shared__ int lcur[NBUCK];
    __shared__ int gbase[NBUCK];
    __shared__ int wsum[8];
    int tid = threadIdx.x;
    int start = blockIdx.x * CHUNK;
    int sz = min(CHUNK, E - start);

    for (int rep = 0; rep < 2; ++rep) {
        asm volatile("" ::: "memory");         // force global re-loads on rep 1
        __syncthreads();
        unsigned dreg[8], sreg[8];
        hist[tid] = 0;
#pragma unroll
        for (int c = 0; c < 8; ++c) {          // compile-time idx -> VGPRs
            int i = tid + c * 512;
            if (i < sz) {
                dreg[c] = (unsigned)dst[start + i];
                sreg[c] = (unsigned)src[start + i];
            } else {
                dreg[c] = 0xFFFFFFFFu;         // sentinel (real d < N)
            }
        }
        __syncthreads();
#pragma unroll
        for (int c = 0; c < 8; ++c)
            if (dreg[c] != 0xFFFFFFFFu)
                atomicAdd(&hist[dreg[c] / (unsigned)NPB], 1);
        __syncthreads();
        int v = hist[tid];
        int excl = excl_scan_512(v, wsum, tid);
        lstart[tid] = excl;
        lcur[tid] = 0;
        if (rep == 0)
            gbase[tid] = atomicAdd(&bcur[tid], v);  // reservation once only
        __syncthreads();
#pragma unroll
        for (int c = 0; c < 8; ++c) {
            if (dreg[c] == 0xFFFFFFFFu) continue;
            unsigned d = dreg[c];
            unsigned b = d / (unsigned)NPB;
            unsigned loc = d - b * (unsigned)NPB;
            int pos = atomicAdd(&lcur[b], 1);
            int si = lstart[b] + pos;
            packed[si] = (loc << 20) | sreg[c];
            buckb[si] = (unsigned short)b;
        }
        __syncthreads();
        for (int i = tid; i < sz; i += 512) {  // bucket-contiguous bulk write
            unsigned b = buckb[i];
            int dsti = gbase[b] + (i - lstart[b]);
            if (dsti < BCAP)
                staging[(size_t)b * BCAP + dsti] = packed[i];
        }
    }
}

// One block: exclusive prefix of clamped bucket sizes -> bbase[NBUCK].
__global__ __launch_bounds__(512) void bbase_kernel(
        const int* __restrict__ bcur, int* __restrict__ bbase) {
    __shared__ int wsum[8];
    int tid = threadIdx.x;
    int v = min(bcur[tid], BCAP);
    bbase[tid] = excl_scan_512(v, wsum, tid);
}

// Phase B: one block per bucket; hist + wave-scan -> CSR. R25: body x2.
__global__ __launch_bounds__(512) void buildB_kernel(
        const int* __restrict__ bcur, const int* __restrict__ bbase,
        const unsigned* __restrict__ staging,
        int* __restrict__ offs, int* __restrict__ counts,
        float* __restrict__ dinv, int* __restrict__ csr_src,
        int N, int NPB) {
    __shared__ int hist[512];
    __shared__ int cur[512];
    __shared__ int wsum[8];
    int b = blockIdx.x;
    int tid = threadIdx.x;
    int sz = min(bcur[b], BCAP);
    int base = bbase[b];
    int n0 = b * NPB;
    int nn = min(NPB, N - n0);
    const unsigned* se = staging + (size_t)b * BCAP;

    for (int rep = 0; rep < 2; ++rep) {
        asm volatile("" ::: "memory");
        __syncthreads();
        unsigned preg[16];                     // BCAP/512 = 16 covers any sz
        hist[tid] = 0;
#pragma unroll
        for (int c = 0; c < 16; ++c) {
            int i = tid + c * 512;
            preg[c] = (i < sz) ? se[i] : 0xFFFFFFFFu;
        }
        __syncthreads();
#pragma unroll
        for (int c = 0; c < 16; ++c)
            if (preg[c] != 0xFFFFFFFFu) atomicAdd(&hist[preg[c] >> 20], 1);
        __syncthreads();
        int h = hist[tid];
        int excl = excl_scan_512(h, wsum, tid);
        cur[tid] = excl;
        if (tid < nn) {
            int node = n0 + tid;
            offs[node] = base + excl;
            counts[node] = h;
            dinv[node] = rsqrtf((float)(h + 1));   // +1 self-loop
        }
        __syncthreads();
#pragma unroll
        for (int c = 0; c < 16; ++c) {
            unsigned p = preg[c];
            if (p == 0xFFFFFFFFu) continue;
            int pos = atomicAdd(&cur[p >> 20], 1);
            csr_src[base + pos] = (int)(p & 0xFFFFFu);
        }
    }
}

// xwd(bf16) = (x @ W1) * dinv[node].  4 thr/node x 8 cols x 2 nodes/thr.
// R25: compute+store body x2.
__global__ __launch_bounds__(256) void gemm1_kernel(
        const float* __restrict__ x, const float* __restrict__ W1,
        const float* __restrict__ dinv, unsigned* __restrict__ xwd, int N) {
    __shared__ float ws_[128 * 32];
    for (int i = threadIdx.x; i < 128 * 32; i += 256) ws_[i] = W1[i];
    __syncthreads();
    int t = threadIdx.x;
    int jq = (t & 3) * 8;  // 8 output cols
    int n0 = blockIdx.x * 128 + (t >> 2) * 2;
    if (n0 >= N) return;
    int nc0 = min(n0 + 0, N - 1);
    int nc1 = min(n0 + 1, N - 1);
    const float4* xr0 = (const float4*)(x + (size_t)nc0 * 128);
    const float4* xr1 = (const float4*)(x + (size_t)nc1 * 128);
    for (int rep = 0; rep < 2; ++rep) {
        asm volatile("" ::: "memory");
        float acc[2][8];
#pragma unroll
        for (int n = 0; n < 2; ++n)
#pragma unroll
            for (int j = 0; j < 8; ++j) acc[n][j] = 0.0f;
#pragma unroll 2
        for (int k4 = 0; k4 < 32; ++k4) {
            const float* wb = ws_ + (k4 * 4) * 32 + jq;
            float4 a0 = *(const float4*)(wb);
            float4 a1 = *(const float4*)(wb + 4);
            float4 b0 = *(const float4*)(wb + 32);
            float4 b1v = *(const float4*)(wb + 36);
            float4 c0 = *(const float4*)(wb + 64);
            float4 c1 = *(const float4*)(wb + 68);
            float4 d0 = *(const float4*)(wb + 96);
            float4 d1 = *(const float4*)(wb + 100);
            float4 xv0 = xr0[k4];
            float4 xv1 = xr1[k4];
#pragma unroll
            for (int n = 0; n < 2; ++n) {
                float4 xv = (n == 0) ? xv0 : xv1;
                acc[n][0] += xv.x * a0.x + xv.y * b0.x + xv.z * c0.x + xv.w * d0.x;
                acc[n][1] += xv.x * a0.y + xv.y * b0.y + xv.z * c0.y + xv.w * d0.y;
                acc[n][2] += xv.x * a0.z + xv.y * b0.z + xv.z * c0.z + xv.w * d0.z;
                acc[n][3] += xv.x * a0.w + xv.y * b0.w + xv.z * c0.w + xv.w * d0.w;
                acc[n][4] += xv.x * a1.x + xv.y * b1v.x + xv.z * c1.x + xv.w * d1.x;
                acc[n][5] += xv.x * a1.y + xv.y * b1v.y + xv.z * c1.y + xv.w * d1.y;
                acc[n][6] += xv.x * a1.z + xv.y * b1v.z + xv.z * c1.z + xv.w * d1.z;
                acc[n][7] += xv.x * a1.w + xv.y * b1v.w + xv.z * c1.w + xv.w * d1.w;
            }
        }
#pragma unroll
        for (int n = 0; n < 2; ++n) {
            int node = n0 + n;
            if (node >= N) break;
            float d = dinv[node];
            unsigned pk0 = f2bf(acc[n][0] * d) | (f2bf(acc[n][1] * d) << 16);
            unsigned pk1 = f2bf(acc[n][2] * d) | (f2bf(acc[n][3] * d) << 16);
            unsigned pk2 = f2bf(acc[n][4] * d) | (f2bf(acc[n][5] * d) << 16);
            unsigned pk3 = f2bf(acc[n][6] * d) | (f2bf(acc[n][7] * d) << 16);
            ((uint4*)(xwd + (size_t)node * 16))[t & 3] = make_uint4(pk0, pk1, pk2, pk3);
        }
    }
}

// Layer-1 aggregate FUSED with gemm2 (single-pass reference, unchanged).
__global__ __launch_bounds__(256) void aggF_kernel(
        const int* __restrict__ offs, const int* __restrict__ counts,
        const int* __restrict__ csr_src, const float* __restrict__ dinv,
        const unsigned* __restrict__ xwd, const float* __restrict__ b1,
        const float* __restrict__ W2, unsigned* __restrict__ h2wd, int N) {
    __shared__ float ws2[32 * 16];
    for (int i = threadIdx.x; i < 512; i += 256) ws2[i] = W2[i];
    __syncthreads();
    int t = threadIdx.x;
    int q = t & 3;                       // 16B slice
    int node = blockIdx.x * 64 + (t >> 2);
    if (node >= N) return;
    int off = offs[node];
    int deg = counts[node];
    float acc[8];
    {
        uint4 v = ((const uint4*)(xwd + (size_t)node * 16))[q];  // self term
        acc[0] = bflo(v.x); acc[1] = bfhi(v.x);
        acc[2] = bflo(v.y); acc[3] = bfhi(v.y);
        acc[4] = bflo(v.z); acc[5] = bfhi(v.z);
        acc[6] = bflo(v.w); acc[7] = bfhi(v.w);
    }
    int deg8 = deg & ~7;
    int idx[8];
    if (deg8 > 0) {
#pragma unroll
        for (int c = 0; c < 8; ++c) idx[c] = csr_src[off + c];
    }
    int i = 0;
    while (i < deg8) {
        uint4 v0 = ((const uint4*)(xwd + (size_t)idx[0] * 16))[q];
        uint4 v1 = ((const uint4*)(xwd + (size_t)idx[1] * 16))[q];
        uint4 v2 = ((const uint4*)(xwd + (size_t)idx[2] * 16))[q];
        uint4 v3 = ((const uint4*)(xwd + (size_t)idx[3] * 16))[q];
        uint4 v4 = ((const uint4*)(xwd + (size_t)idx[4] * 16))[q];
        uint4 v5 = ((const uint4*)(xwd + (size_t)idx[5] * 16))[q];
        uint4 v6 = ((const uint4*)(xwd + (size_t)idx[6] * 16))[q];
        uint4 v7 = ((const uint4*)(xwd + (size_t)idx[7] * 16))[q];
        i += 8;
        if (i < deg8) {                  // prefetch next batch's indices
#pragma unroll
            for (int c = 0; c < 8; ++c) idx[c] = csr_src[off + i + c];
        }
        acc[0] += ((bflo(v0.x) + bflo(v1.x)) + (bflo(v2.x) + bflo(v3.x)))
                + ((bflo(v4.x) + bflo(v5.x)) + (bflo(v6.x) + bflo(v7.x)));
        acc[1] += ((bfhi(v0.x) + bfhi(v1.x)) + (bfhi(v2.x) + bfhi(v3.x)))
                + ((bfhi(v4.x) + bfhi(v5.x)) + (bfhi(v6.x) + bfhi(v7.x)));
        acc[2] += ((bflo(v0.y) + bflo(v1.y)) + (bflo(v2.y) + bflo(v3.y)))
                + ((bflo(v4.y) + bflo(v5.y)) + (bflo(v6.y) + bflo(v7.y)));
        acc[3] += ((bfhi(v0.y) + bfhi(v1.y)) + (bfhi(v2.y) + bfhi(v3.y)))
                + ((bfhi(v4.y) + bfhi(v5.y)) + (bfhi(v6.y) + bfhi(v7.y)));
        acc[4] += ((bflo(v0.z) + bflo(v1.z)) + (bflo(v2.z) + bflo(v3.z)))
                + ((bflo(v4.z) + bflo(v5.z)) + (bflo(v6.z) + bflo(v7.z)));
        acc[5] += ((bfhi(v0.z) + bfhi(v1.z)) + (bfhi(v2.z) + bfhi(v3.z)))
                + ((bfhi(v4.z) + bfhi(v5.z)) + (bfhi(v6.z) + bfhi(v7.z)));
        acc[6] += ((bflo(v0.w) + bflo(v1.w)) + (bflo(v2.w) + bflo(v3.w)))
                + ((bflo(v4.w) + bflo(v5.w)) + (bflo(v6.w) + bflo(v7.w)));
        acc[7] += ((bfhi(v0.w) + bfhi(v1.w)) + (bfhi(v2.w) + bfhi(v3.w)))
                + ((bfhi(v4.w) + bfhi(v5.w)) + (bfhi(v6.w) + bfhi(v7.w)));
    }
    for (; i < deg; ++i) {
        int s = csr_src[off + i];
        uint4 v = ((const uint4*)(xwd + (size_t)s * 16))[q];
        acc[0] += bflo(v.x); acc[1] += bfhi(v.x);
        acc[2] += bflo(v.y); acc[3] += bfhi(v.y);
        acc[4] += bflo(v.z); acc[5] += bfhi(v.z);
        acc[6] += bflo(v.w); acc[7] += bfhi(v.w);
    }
    float dv = dinv[node];
    // fused gemm2: lane q owns k = q*8..q*8+7 of the 32-dim hidden vector
    float part[16];
#pragma unroll
    for (int j = 0; j < 16; ++j) part[j] = 0.0f;
    const float* bq = b1 + q * 8;
#pragma unroll
    for (int k = 0; k < 8; ++k) {
        float h = fmaxf(acc[k] * dv + bq[k], 0.0f);
        const float* wr = ws2 + (q * 8 + k) * 16;
        float4 w0 = *(const float4*)(wr);
        float4 w1 = *(const float4*)(wr + 4);
        float4 w2 = *(const float4*)(wr + 8);
        float4 w3 = *(const float4*)(wr + 12);
        part[0]  += h * w0.x; part[1]  += h * w0.y; part[2]  += h * w0.z; part[3]  += h * w0.w;
        part[4]  += h * w1.x; part[5]  += h * w1.y; part[6]  += h * w1.z; part[7]  += h * w1.w;
        part[8]  += h * w2.x; part[9]  += h * w2.y; part[10] += h * w2.z; part[11] += h * w2.w;
        part[12] += h * w3.x; part[13] += h * w3.y; part[14] += h * w3.z; part[15] += h * w3.w;
    }
    // half-exchange butterfly over the quad: 8 + 4 shfl total.
    float p8[8];
#pragma unroll
    for (int j = 0; j < 8; ++j) {
        float send = (q & 1) ? part[j] : part[j + 8];
        float keep = (q & 1) ? part[j + 8] : part[j];
        p8[j] = keep + __shfl_xor(send, 1, 64);
    }
    float p4[4];
#pragma unroll
    for (int j = 0; j < 4; ++j) {
        float send = (q & 2) ? p8[j] : p8[j + 4];
        float keep = (q & 2) ? p8[j + 4] : p8[j];
        p4[j] = keep + __shfl_xor(send, 2, 64);
    }
    unsigned pk0 = f2bf(p4[0] * dv) | (f2bf(p4[1] * dv) << 16);
    unsigned pk1 = f2bf(p4[2] * dv) | (f2bf(p4[3] * dv) << 16);
    int slot = ((q & 1) << 1) | ((q >> 1) & 1);   // col base /4: q0->0 q1->2 q2->1 q3->3
    ((uint2*)(h2wd + (size_t)node * 8))[slot] = make_uint2(pk0, pk1);
}

// Layer-2 aggregate + fused head, 2 lanes/node, x8 pipelined. R25: body x2.
__global__ __launch_bounds__(256) void aggS16f_kernel(
        const int* __restrict__ offs, const int* __restrict__ counts,
        const int* __restrict__ csr_src, const float* __restrict__ dinv,
        const unsigned* __restrict__ h2wd,
        const float* __restrict__ b2, const float* __restrict__ Wf,
        const float* __restrict__ bf, float* __restrict__ out, int N) {
    __shared__ float bs_[16];
    __shared__ float wf_[16];
    __shared__ float bfv;
    int t = threadIdx.x;
    if (t < 16) { bs_[t] = b2[t]; wf_[t] = Wf[t]; }
    if (t == 0) bfv = bf[0];
    __syncthreads();
    int q = t & 1;                        // 16B slice (8 feats)
    int node = blockIdx.x * 128 + (t >> 1);
    if (node >= N) return;
    int off = offs[node];
    int deg = counts[node];
    for (int rep = 0; rep < 2; ++rep) {
        asm volatile("" ::: "memory");
        float acc[8];
        {
            uint4 v = ((const uint4*)(h2wd + (size_t)node * 8))[q];  // self
            acc[0] = bflo(v.x); acc[1] = bfhi(v.x);
            acc[2] = bflo(v.y); acc[3] = bfhi(v.y);
            acc[4] = bflo(v.z); acc[5] = bfhi(v.z);
            acc[6] = bflo(v.w); acc[7] = bfhi(v.w);
        }
        int deg8 = deg & ~7;
        int idx[8];
        if (deg8 > 0) {
#pragma unroll
            for (int c = 0; c < 8; ++c) idx[c] = csr_src[off + c];
        }
        int i = 0;
        while (i < deg8) {
            uint4 v0 = ((const uint4*)(h2wd + (size_t)idx[0] * 8))[q];
            uint4 v1 = ((const uint4*)(h2wd + (size_t)idx[1] * 8))[q];
            uint4 v2 = ((const uint4*)(h2wd + (size_t)idx[2] * 8))[q];
            uint4 v3 = ((const uint4*)(h2wd + (size_t)idx[3] * 8))[q];
            uint4 v4 = ((const uint4*)(h2wd + (size_t)idx[4] * 8))[q];
            uint4 v5 = ((const uint4*)(h2wd + (size_t)idx[5] * 8))[q];
            uint4 v6 = ((const uint4*)(h2wd + (size_t)idx[6] * 8))[q];
            uint4 v7 = ((const uint4*)(h2wd + (size_t)idx[7] * 8))[q];
            i += 8;
            if (i < deg8) {
#pragma unroll
                for (int c = 0; c < 8; ++c) idx[c] = csr_src[off + i + c];
            }
            acc[0] += ((bflo(v0.x) + bflo(v1.x)) + (bflo(v2.x) + bflo(v3.x)))
                    + ((bflo(v4.x) + bflo(v5.x)) + (bflo(v6.x) + bflo(v7.x)));
            acc[1] += ((bfhi(v0.x) + bfhi(v1.x)) + (bfhi(v2.x) + bfhi(v3.x)))
                    + ((bfhi(v4.x) + bfhi(v5.x)) + (bfhi(v6.x) + bfhi(v7.x)));
            acc[2] += ((bflo(v0.y) + bflo(v1.y)) + (bflo(v2.y) + bflo(v3.y)))
                    + ((bflo(v4.y) + bflo(v5.y)) + (bflo(v6.y) + bflo(v7.y)));
            acc[3] += ((bfhi(v0.y) + bfhi(v1.y)) + (bfhi(v2.y) + bfhi(v3.y)))
                    + ((bfhi(v4.y) + bfhi(v5.y)) + (bfhi(v6.y) + bfhi(v7.y)));
            acc[4] += ((bflo(v0.z) + bflo(v1.z)) + (bflo(v2.z) + bflo(v3.z)))
                    + ((bflo(v4.z) + bflo(v5.z)) + (bflo(v6.z) + bflo(v7.z)));
            acc[5] += ((bfhi(v0.z) + bfhi(v1.z)) + (bfhi(v2.z) + bfhi(v3.z)))
                    + ((bfhi(v4.z) + bfhi(v5.z)) + (bfhi(v6.z) + bfhi(v7.z)));
            acc[6] += ((bflo(v0.w) + bflo(v1.w)) + (bflo(v2.w) + bflo(v3.w)))
                    + ((bflo(v4.w) + bflo(v5.w)) + (bflo(v6.w) + bflo(v7.w)));
            acc[7] += ((bfhi(v0.w) + bfhi(v1.w)) + (bfhi(v2.w) + bfhi(v3.w)))
                    + ((bfhi(v4.w) + bfhi(v5.w)) + (bfhi(v6.w) + bfhi(v7.w)));
        }
        for (; i < deg; ++i) {
            int s = csr_src[off + i];
            uint4 v = ((const uint4*)(h2wd + (size_t)s * 8))[q];
            acc[0] += bflo(v.x); acc[1] += bfhi(v.x);
            acc[2] += bflo(v.y); acc[3] += bfhi(v.y);
            acc[4] += bflo(v.z); acc[5] += bfhi(v.z);
            acc[6] += bflo(v.w); acc[7] += bfhi(v.w);
        }
        // fused head: out[node] = relu(acc*dv + b2) . Wf + bf
        float dv = dinv[node];
        const float* bq = bs_ + q * 8;
        const float* wq = wf_ + q * 8;
        float part = 0.f;
#pragma unroll
        for (int k = 0; k < 8; ++k)
            part += fmaxf(acc[k] * dv + bq[k], 0.f) * wq[k];
        part += __shfl_xor(part, 1, 64);  // combine the pair's halves
        if (q == 0) out[node] = part + bfv;
    }
}

extern "C" void kernel_launch(void* const* d_in, const int* in_sizes, int n_in,
                              void* d_out, int out_size, void* d_ws, size_t ws_size,
                              hipStream_t stream) {
    const float* x  = (const float*)d_in[0];
    const int*   ei = (const int*)d_in[1];
    const float* W1 = (const float*)d_in[2];
    const float* b1 = (const float*)d_in[3];
    const float* W2 = (const float*)d_in[4];
    const float* b2 = (const float*)d_in[5];
    const float* Wf = (const float*)d_in[6];
    const float* bf = (const float*)d_in[7];

    int N = in_sizes[0] / 128;
    int E = in_sizes[1] / 2;
    const int* src = ei;       // edge_index[0]
    const int* dst = ei + E;   // edge_index[1]
    int NPB = (N + NBUCK - 1) / NBUCK;  // 196 for N=100k

    // Workspace layout
    size_t Np = ((size_t)N + 3) & ~(size_t)3;
    size_t Ep = ((size_t)E + 3) & ~(size_t)3;
    int* wsI      = (int*)d_ws;
    int* counts   = wsI;                 // Np
    int* offs     = counts + Np;         // Np
    int* bcur     = offs + Np;           // NBUCK
    int* bbase    = bcur + NBUCK;        // NBUCK
    int* csr_src  = bbase + NBUCK;       // Ep
    float* dinv   = (float*)(csr_src + Ep);      // Np
    unsigned* xwd = (unsigned*)(dinv + Np);      // 16*Np u32 (bf16, 64B rows)
    unsigned* staging = xwd + 16 * Np;           // NBUCK*BCAP u32 = 16.8 MB
    // h2wd (8*N u32 = 3.2 MB) aliases staging: staging written by binA2,
    // read last by buildB; h2wd first written by aggF (later). No overlap.
    unsigned* h2wd = staging;
    float* out    = (float*)d_out;

    int nbC  = (E + CHUNK - 1) / CHUNK;  // 782
    int nbG1 = (N + 127) / 128;          // 782 (2 nodes/thread)
    int nbA32 = (N + 63) / 64;   // 64 nodes/block (4 lanes/node)
    int nbA16 = (N + 127) / 128; // 128 nodes/block (2 lanes/node)

    hipMemsetAsync(bcur, 0, NBUCK * sizeof(int), stream);
    binA2_kernel<<<nbC, 512, 0, stream>>>(src, dst, bcur, staging, E, NPB);
    bbase_kernel<<<1, 512, 0, stream>>>(bcur, bbase);
    buildB_kernel<<<NBUCK, 512, 0, stream>>>(bcur, bbase, staging, offs, counts,
                                             dinv, csr_src, N, NPB);
    gemm1_kernel<<<nbG1, 256, 0, stream>>>(x, W1, dinv, xwd, N);
    aggF_kernel<<<nbA32, 256, 0, stream>>>(offs, counts, csr_src, dinv, xwd,
                                           b1, W2, h2wd, N);
    aggS16f_kernel<<<nbA16, 256, 0, stream>>>(offs, counts, csr_src, dinv, h2wd,
                                              b2, Wf, bf, out, N);
}

// Round 11
// 245.537 us; speedup vs baseline: 2.0089x; 1.2451x over previous
//
#include <hip/hip_runtime.h>

// GCN forward via two-level CSR build + gather aggregation.
// Lessons ledger:
//   R4/R9:  atomic float aggregation (global) loses 5-10x to register gather.
//   R15:    ...and LDS float atomics lose too (591us). Register accum only.
//   R17:    scattered 4B global writes forbidden (15x partial-line write
//           amplification across 8 non-coherent L2s -> 300us scatter).
//   R13/18/20: gather per-lane MLP exhausted at x8 batches (51->45us).
//   R19:    blind micro-opts on never-profiled kernels were null 3x.
//   R22:    top-5 visibility threshold = 41.5us harness fill.
//   R23/24: cooperative fused build intrinsically ~270us. Abandoned.
//   R26 (R10 measurement): TRUE accounting of the 244.7us baseline:
//           aggF 45 + aggS16f 27 + (binA2+buildB+gemm1) 34 + FIXED ~139
//           (harness fill 41.5 + graph/dispatch overhead). The build was
//           never the problem; 57% of runtime is harness-fixed.
//   R27 (this round): aggF counters (VALU 21%, HBM 32%, occ 30%) = nothing
//           saturated -> add WAVE-level parallelism: edge-lists split across
//           2x lanes (aggF 8 lanes/node, aggS16f 4), halves combined with
//           shfl_xor before the nonlinear epilogue. bbase folded into buildB.
// Pipeline (6 dispatches):
//   memset(bcur)
//   binA2: per-block LDS radix partition -> 512 dst-range buckets.
//   buildB: inline bucket-base scan + per-bucket hist/scan -> CSR + dinv.
//   gemm1: xwd = (x@W1)*dinv, bf16 64B rows, 4 thr/node x 2 nodes/thr.
//   aggF: layer-1 gather (8 lanes/node: 4 slices x 2 edge-halves, x8
//         pipelined) + fused gemm2 -> h2wd.
//   aggS16f: layer-2 gather (4 lanes/node: 2 slices x 2 halves) + head.

#define TPB 256
#define NBUCK 512
#define BCAP 8192    // bucket capacity; mean ~6272, sd ~79 -> 24 sigma margin
#define CHUNK 4096   // edges per binA2 block -> 782 blocks

__device__ __forceinline__ unsigned f2bf(float f) {  // RNE fp32->bf16
    unsigned u = __float_as_uint(f);
    return (u + 0x7FFFu + ((u >> 16) & 1u)) >> 16;
}
__device__ __forceinline__ float bflo(unsigned u) { return __uint_as_float(u << 16); }
__device__ __forceinline__ float bfhi(unsigned u) { return __uint_as_float(u & 0xFFFF0000u); }

// Exclusive scan over 512 values (one per thread) using wave shfl scans.
__device__ __forceinline__ int excl_scan_512(int v, int* wsum, int tid) {
    int lane = tid & 63, wv = tid >> 6;
    int x = v;
#pragma unroll
    for (int d = 1; d < 64; d <<= 1) {
        int y = __shfl_up(x, d, 64);
        if (lane >= d) x += y;
    }
    if (lane == 63) wsum[wv] = x;          // inclusive wave sum
    __syncthreads();
    if (tid < 64) {
        int s = (lane < 8) ? wsum[lane] : 0;
#pragma unroll
        for (int d = 1; d < 8; d <<= 1) {
            int y = __shfl_up(s, d, 64);
            if (lane >= d) s += y;
        }
        if (lane < 8) wsum[lane] = s;      // inclusive across waves
    }
    __syncthreads();
    int base = (wv > 0) ? wsum[wv - 1] : 0;
    return base + x - v;                   // exclusive prefix
}

// Phase A: block-local radix partition, bulk append to global staging.
__global__ __launch_bounds__(512) void binA2_kernel(
        const int* __restrict__ src, const int* __restrict__ dst,
        int* __restrict__ bcur, unsigned* __restrict__ staging, int E, int NPB) {
    __shared__ unsigned packed[CHUNK];         // 16 KB
    __shared__ unsigned short buckb[CHUNK];    // 8 KB
    __shared__ int hist[NBUCK];                // 2 KB each
    __shared__ int lstart[NBUCK];
    __shared__ int lcur[NBUCK];
    __shared__ int gbase[NBUCK];
    __shared__ int wsum[8];
    int tid = threadIdx.x;
    int start = blockIdx.x * CHUNK;
    int sz = min(CHUNK, E - start);

    unsigned dreg[8], sreg[8];
    hist[tid] = 0;
#pragma unroll
    for (int c = 0; c < 8; ++c) {              // compile-time idx -> VGPRs
        int i = tid + c * 512;
        if (i < sz) {
            dreg[c] = (unsigned)dst[start + i];
            sreg[c] = (unsigned)src[start + i];
        } else {
            dreg[c] = 0xFFFFFFFFu;             // sentinel (real d < N)
        }
    }
    __syncthreads();
#pragma unroll
    for (int c = 0; c < 8; ++c)
        if (dreg[c] != 0xFFFFFFFFu) atomicAdd(&hist[dreg[c] / (unsigned)NPB], 1);
    __syncthreads();
    int v = hist[tid];
    int excl = excl_scan_512(v, wsum, tid);
    lstart[tid] = excl;
    lcur[tid] = 0;
    gbase[tid] = atomicAdd(&bcur[tid], v);     // one reservation per (block,bucket)
    __syncthreads();
#pragma unroll
    for (int c = 0; c < 8; ++c) {
        if (dreg[c] == 0xFFFFFFFFu) continue;
        unsigned d = dreg[c];
        unsigned b = d / (unsigned)NPB;
        unsigned loc = d - b * (unsigned)NPB;
        int pos = atomicAdd(&lcur[b], 1);
        int si = lstart[b] + pos;
        packed[si] = (loc << 20) | sreg[c];    // loc<=195 (12b), src<2^17
        buckb[si] = (unsigned short)b;
    }
    __syncthreads();
    for (int i = tid; i < sz; i += 512) {      // bucket-contiguous bulk write
        unsigned b = buckb[i];
        int dsti = gbase[b] + (i - lstart[b]);
        if (dsti < BCAP)
            staging[(size_t)b * BCAP + dsti] = packed[i];
    }
}

// Phase B: one block per bucket; inline bucket-base scan (R27: bbase kernel
// folded in, one shared int); hist + wave-scan -> CSR placement.
__global__ __launch_bounds__(512) void buildB_kernel(
        const int* __restrict__ bcur, const unsigned* __restrict__ staging,
        int* __restrict__ offs, int* __restrict__ counts,
        float* __restrict__ dinv, int* __restrict__ csr_src,
        int N, int NPB) {
    __shared__ int hist[512];
    __shared__ int cur[512];
    __shared__ int wsum[8];
    __shared__ int base_sh;
    int b = blockIdx.x;
    int tid = threadIdx.x;
    // inline bbase: exclusive prefix of clamped bucket sizes; keep entry b
    int myv = min(bcur[tid], BCAP);
    int bexcl = excl_scan_512(myv, wsum, tid);
    if (tid == b) base_sh = bexcl;
    int sz = min(bcur[b], BCAP);
    int n0 = b * NPB;
    int nn = min(NPB, N - n0);
    const unsigned* se = staging + (size_t)b * BCAP;

    unsigned preg[16];                         // BCAP/512 = 16 covers any sz
    hist[tid] = 0;
#pragma unroll
    for (int c = 0; c < 16; ++c) {
        int i = tid + c * 512;
        preg[c] = (i < sz) ? se[i] : 0xFFFFFFFFu;
    }
    __syncthreads();
    int base = base_sh;
#pragma unroll
    for (int c = 0; c < 16; ++c)
        if (preg[c] != 0xFFFFFFFFu) atomicAdd(&hist[preg[c] >> 20], 1);
    __syncthreads();
    int h = hist[tid];
    int excl = excl_scan_512(h, wsum, tid);
    cur[tid] = excl;
    if (tid < nn) {
        int node = n0 + tid;
        offs[node] = base + excl;
        counts[node] = h;
        dinv[node] = rsqrtf((float)(h + 1));   // +1 self-loop
    }
    __syncthreads();
#pragma unroll
    for (int c = 0; c < 16; ++c) {
        unsigned p = preg[c];
        if (p == 0xFFFFFFFFu) continue;
        int pos = atomicAdd(&cur[p >> 20], 1);
        csr_src[base + pos] = (int)(p & 0xFFFFFu);
    }
}

// xwd(bf16) = (x @ W1) * dinv[node].  4 threads/node x 8 cols x 2 nodes/thr.
__global__ __launch_bounds__(256) void gemm1_kernel(
        const float* __restrict__ x, const float* __restrict__ W1,
        const float* __restrict__ dinv, unsigned* __restrict__ xwd, int N) {
    __shared__ float ws_[128 * 32];
    for (int i = threadIdx.x; i < 128 * 32; i += 256) ws_[i] = W1[i];
    __syncthreads();
    int t = threadIdx.x;
    int jq = (t & 3) * 8;  // 8 output cols
    int n0 = blockIdx.x * 128 + (t >> 2) * 2;
    if (n0 >= N) return;
    int nc0 = min(n0 + 0, N - 1);
    int nc1 = min(n0 + 1, N - 1);
    const float4* xr0 = (const float4*)(x + (size_t)nc0 * 128);
    const float4* xr1 = (const float4*)(x + (size_t)nc1 * 128);
    float acc[2][8];
#pragma unroll
    for (int n = 0; n < 2; ++n)
#pragma unroll
        for (int j = 0; j < 8; ++j) acc[n][j] = 0.0f;
#pragma unroll 2
    for (int k4 = 0; k4 < 32; ++k4) {
        const float* wb = ws_ + (k4 * 4) * 32 + jq;
        float4 a0 = *(const float4*)(wb);
        float4 a1 = *(const float4*)(wb + 4);
        float4 b0 = *(const float4*)(wb + 32);
        float4 b1v = *(const float4*)(wb + 36);
        float4 c0 = *(const float4*)(wb + 64);
        float4 c1 = *(const float4*)(wb + 68);
        float4 d0 = *(const float4*)(wb + 96);
        float4 d1 = *(const float4*)(wb + 100);
        float4 xv0 = xr0[k4];
        float4 xv1 = xr1[k4];
#pragma unroll
        for (int n = 0; n < 2; ++n) {
            float4 xv = (n == 0) ? xv0 : xv1;
            acc[n][0] += xv.x * a0.x + xv.y * b0.x + xv.z * c0.x + xv.w * d0.x;
            acc[n][1] += xv.x * a0.y + xv.y * b0.y + xv.z * c0.y + xv.w * d0.y;
            acc[n][2] += xv.x * a0.z + xv.y * b0.z + xv.z * c0.z + xv.w * d0.z;
            acc[n][3] += xv.x * a0.w + xv.y * b0.w + xv.z * c0.w + xv.w * d0.w;
            acc[n][4] += xv.x * a1.x + xv.y * b1v.x + xv.z * c1.x + xv.w * d1.x;
            acc[n][5] += xv.x * a1.y + xv.y * b1v.y + xv.z * c1.y + xv.w * d1.y;
            acc[n][6] += xv.x * a1.z + xv.y * b1v.z + xv.z * c1.z + xv.w * d1.z;
            acc[n][7] += xv.x * a1.w + xv.y * b1v.w + xv.z * c1.w + xv.w * d1.w;
        }
    }
#pragma unroll
    for (int n = 0; n < 2; ++n) {
        int node = n0 + n;
        if (node >= N) break;
        float d = dinv[node];
        unsigned pk0 = f2bf(acc[n][0] * d) | (f2bf(acc[n][1] * d) << 16);
        unsigned pk1 = f2bf(acc[n][2] * d) | (f2bf(acc[n][3] * d) << 16);
        unsigned pk2 = f2bf(acc[n][4] * d) | (f2bf(acc[n][5] * d) << 16);
        unsigned pk3 = f2bf(acc[n][6] * d) | (f2bf(acc[n][7] * d) << 16);
        ((uint4*)(xwd + (size_t)node * 16))[t & 3] = make_uint4(pk0, pk1, pk2, pk3);
    }
}

// Layer-1 aggregate FUSED with gemm2.  R27: 8 lanes/node = 4 slices (q=t&3)
// x 2 edge-halves (h=bit2); x8 pipelined gather per half; halves combined
// via shfl_xor(.,4) BEFORE the nonlinear epilogue; h=0 writes.
__global__ __launch_bounds__(256) void aggF_kernel(
        const int* __restrict__ offs, const int* __restrict__ counts,
        const int* __restrict__ csr_src, const float* __restrict__ dinv,
        const unsigned* __restrict__ xwd, const float* __restrict__ b1,
        const float* __restrict__ W2, unsigned* __restrict__ h2wd, int N) {
    __shared__ float ws2[32 * 16];
    for (int i = threadIdx.x; i < 512; i += 256) ws2[i] = W2[i];
    __syncthreads();
    int t = threadIdx.x;
    int q = t & 3;                       // 16B slice
    int h = (t >> 2) & 1;                // edge-half
    int node = blockIdx.x * 32 + (t >> 3);
    if (node >= N) return;
    int off = offs[node];
    int deg = counts[node];
    int d0 = (deg + 1) >> 1;
    int mydeg = h ? (deg - d0) : d0;
    int myoff = off + (h ? d0 : 0);
    float acc[8];
    if (h == 0) {                        // self term once
        uint4 v = ((const uint4*)(xwd + (size_t)node * 16))[q];
        acc[0] = bflo(v.x); acc[1] = bfhi(v.x);
        acc[2] = bflo(v.y); acc[3] = bfhi(v.y);
        acc[4] = bflo(v.z); acc[5] = bfhi(v.z);
        acc[6] = bflo(v.w); acc[7] = bfhi(v.w);
    } else {
#pragma unroll
        for (int j = 0; j < 8; ++j) acc[j] = 0.0f;
    }
    int deg8 = mydeg & ~7;
    int idx[8];
    if (deg8 > 0) {
#pragma unroll
        for (int c = 0; c < 8; ++c) idx[c] = csr_src[myoff + c];
    }
    int i = 0;
    while (i < deg8) {
        uint4 v0 = ((const uint4*)(xwd + (size_t)idx[0] * 16))[q];
        uint4 v1 = ((const uint4*)(xwd + (size_t)idx[1] * 16))[q];
        uint4 v2 = ((const uint4*)(xwd + (size_t)idx[2] * 16))[q];
        uint4 v3 = ((const uint4*)(xwd + (size_t)idx[3] * 16))[q];
        uint4 v4 = ((const uint4*)(xwd + (size_t)idx[4] * 16))[q];
        uint4 v5 = ((const uint4*)(xwd + (size_t)idx[5] * 16))[q];
        uint4 v6 = ((const uint4*)(xwd + (size_t)idx[6] * 16))[q];
        uint4 v7 = ((const uint4*)(xwd + (size_t)idx[7] * 16))[q];
        i += 8;
        if (i < deg8) {                  // prefetch next batch's indices
#pragma unroll
            for (int c = 0; c < 8; ++c) idx[c] = csr_src[myoff + i + c];
        }
        acc[0] += ((bflo(v0.x) + bflo(v1.x)) + (bflo(v2.x) + bflo(v3.x)))
                + ((bflo(v4.x) + bflo(v5.x)) + (bflo(v6.x) + bflo(v7.x)));
        acc[1] += ((bfhi(v0.x) + bfhi(v1.x)) + (bfhi(v2.x) + bfhi(v3.x)))
                + ((bfhi(v4.x) + bfhi(v5.x)) + (bfhi(v6.x) + bfhi(v7.x)));
        acc[2] += ((bflo(v0.y) + bflo(v1.y)) + (bflo(v2.y) + bflo(v3.y)))
                + ((bflo(v4.y) + bflo(v5.y)) + (bflo(v6.y) + bflo(v7.y)));
        acc[3] += ((bfhi(v0.y) + bfhi(v1.y)) + (bfhi(v2.y) + bfhi(v3.y)))
                + ((bfhi(v4.y) + bfhi(v5.y)) + (bfhi(v6.y) + bfhi(v7.y)));
        acc[4] += ((bflo(v0.z) + bflo(v1.z)) + (bflo(v2.z) + bflo(v3.z)))
                + ((bflo(v4.z) + bflo(v5.z)) + (bflo(v6.z) + bflo(v7.z)));
        acc[5] += ((bfhi(v0.z) + bfhi(v1.z)) + (bfhi(v2.z) + bfhi(v3.z)))
                + ((bfhi(v4.z) + bfhi(v5.z)) + (bfhi(v6.z) + bfhi(v7.z)));
        acc[6] += ((bflo(v0.w) + bflo(v1.w)) + (bflo(v2.w) + bflo(v3.w)))
                + ((bflo(v4.w) + bflo(v5.w)) + (bflo(v6.w) + bflo(v7.w)));
        acc[7] += ((bfhi(v0.w) + bfhi(v1.w)) + (bfhi(v2.w) + bfhi(v3.w)))
                + ((bfhi(v4.w) + bfhi(v5.w)) + (bfhi(v6.w) + bfhi(v7.w)));
    }
    for (; i < mydeg; ++i) {
        int s = csr_src[myoff + i];
        uint4 v = ((const uint4*)(xwd + (size_t)s * 16))[q];
        acc[0] += bflo(v.x); acc[1] += bfhi(v.x);
        acc[2] += bflo(v.y); acc[3] += bfhi(v.y);
        acc[4] += bflo(v.z); acc[5] += bfhi(v.z);
        acc[6] += bflo(v.w); acc[7] += bfhi(v.w);
    }
    // combine edge-halves (linear, safe before relu)
#pragma unroll
    for (int j = 0; j < 8; ++j) acc[j] += __shfl_xor(acc[j], 4, 64);
    float dv = dinv[node];
    // fused gemm2: lane q owns k = q*8..q*8+7 of the 32-dim hidden vector
    float part[16];
#pragma unroll
    for (int j = 0; j < 16; ++j) part[j] = 0.0f;
    const float* bq = b1 + q * 8;
#pragma unroll
    for (int k = 0; k < 8; ++k) {
        float hh = fmaxf(acc[k] * dv + bq[k], 0.0f);
        const float* wr = ws2 + (q * 8 + k) * 16;
        float4 w0 = *(const float4*)(wr);
        float4 w1 = *(const float4*)(wr + 4);
        float4 w2 = *(const float4*)(wr + 8);
        float4 w3 = *(const float4*)(wr + 12);
        part[0]  += hh * w0.x; part[1]  += hh * w0.y; part[2]  += hh * w0.z; part[3]  += hh * w0.w;
        part[4]  += hh * w1.x; part[5]  += hh * w1.y; part[6]  += hh * w1.z; part[7]  += hh * w1.w;
        part[8]  += hh * w2.x; part[9]  += hh * w2.y; part[10] += hh * w2.z; part[11] += hh * w2.w;
        part[12] += hh * w3.x; part[13] += hh * w3.y; part[14] += hh * w3.z; part[15] += hh * w3.w;
    }
    // half-exchange butterfly over the quad: 8 + 4 shfl total (both h copies
    // compute identical values; only h==0 writes).
    float p8[8];
#pragma unroll
    for (int j = 0; j < 8; ++j) {
        float send = (q & 1) ? part[j] : part[j + 8];
        float keep = (q & 1) ? part[j + 8] : part[j];
        p8[j] = keep + __shfl_xor(send, 1, 64);
    }
    float p4[4];
#pragma unroll
    for (int j = 0; j < 4; ++j) {
        float send = (q & 2) ? p8[j] : p8[j + 4];
        float keep = (q & 2) ? p8[j + 4] : p8[j];
        p4[j] = keep + __shfl_xor(send, 2, 64);
    }
    unsigned pk0 = f2bf(p4[0] * dv) | (f2bf(p4[1] * dv) << 16);
    unsigned pk1 = f2bf(p4[2] * dv) | (f2bf(p4[3] * dv) << 16);
    int slot = ((q & 1) << 1) | ((q >> 1) & 1);   // col base /4: q0->0 q1->2 q2->1 q3->3
    if (h == 0)
        ((uint2*)(h2wd + (size_t)node * 8))[slot] = make_uint2(pk0, pk1);
}

// Layer-2 aggregate + fused head.  R27: 4 lanes/node = 2 slices (q=t&1)
// x 2 edge-halves (h=bit1); halves combined via shfl_xor(.,2) before head.
__global__ __launch_bounds__(256) void aggS16f_kernel(
        const int* __restrict__ offs, const int* __restrict__ counts,
        const int* __restrict__ csr_src, const float* __restrict__ dinv,
        const unsigned* __restrict__ h2wd,
        const float* __restrict__ b2, const float* __restrict__ Wf,
        const float* __restrict__ bf, float* __restrict__ out, int N) {
    __shared__ float bs_[16];
    __shared__ float wf_[16];
    __shared__ float bfv;
    int t = threadIdx.x;
    if (t < 16) { bs_[t] = b2[t]; wf_[t] = Wf[t]; }
    if (t == 0) bfv = bf[0];
    __syncthreads();
    int q = t & 1;                        // 16B slice (8 feats)
    int h = (t >> 1) & 1;                 // edge-half
    int node = blockIdx.x * 64 + (t >> 2);
    if (node >= N) return;
    int off = offs[node];
    int deg = counts[node];
    int d0 = (deg + 1) >> 1;
    int mydeg = h ? (deg - d0) : d0;
    int myoff = off + (h ? d0 : 0);
    float acc[8];
    if (h == 0) {                         // self term once
        uint4 v = ((const uint4*)(h2wd + (size_t)node * 8))[q];
        acc[0] = bflo(v.x); acc[1] = bfhi(v.x);
        acc[2] = bflo(v.y); acc[3] = bfhi(v.y);
        acc[4] = bflo(v.z); acc[5] = bfhi(v.z);
        acc[6] = bflo(v.w); acc[7] = bfhi(v.w);
    } else {
#pragma unroll
        for (int j = 0; j < 8; ++j) acc[j] = 0.0f;
    }
    int deg8 = mydeg & ~7;
    int idx[8];
    if (deg8 > 0) {
#pragma unroll
        for (int c = 0; c < 8; ++c) idx[c] = csr_src[myoff + c];
    }
    int i = 0;
    while (i < deg8) {
        uint4 v0 = ((const uint4*)(h2wd + (size_t)idx[0] * 8))[q];
        uint4 v1 = ((const uint4*)(h2wd + (size_t)idx[1] * 8))[q];
        uint4 v2 = ((const uint4*)(h2wd + (size_t)idx[2] * 8))[q];
        uint4 v3 = ((const uint4*)(h2wd + (size_t)idx[3] * 8))[q];
        uint4 v4 = ((const uint4*)(h2wd + (size_t)idx[4] * 8))[q];
        uint4 v5 = ((const uint4*)(h2wd + (size_t)idx[5] * 8))[q];
        uint4 v6 = ((const uint4*)(h2wd + (size_t)idx[6] * 8))[q];
        uint4 v7 = ((const uint4*)(h2wd + (size_t)idx[7] * 8))[q];
        i += 8;
        if (i < deg8) {
#pragma unroll
            for (int c = 0; c < 8; ++c) idx[c] = csr_src[myoff + i + c];
        }
        acc[0] += ((bflo(v0.x) + bflo(v1.x)) + (bflo(v2.x) + bflo(v3.x)))
                + ((bflo(v4.x) + bflo(v5.x)) + (bflo(v6.x) + bflo(v7.x)));
        acc[1] += ((bfhi(v0.x) + bfhi(v1.x)) + (bfhi(v2.x) + bfhi(v3.x)))
                + ((bfhi(v4.x) + bfhi(v5.x)) + (bfhi(v6.x) + bfhi(v7.x)));
        acc[2] += ((bflo(v0.y) + bflo(v1.y)) + (bflo(v2.y) + bflo(v3.y)))
                + ((bflo(v4.y) + bflo(v5.y)) + (bflo(v6.y) + bflo(v7.y)));
        acc[3] += ((bfhi(v0.y) + bfhi(v1.y)) + (bfhi(v2.y) + bfhi(v3.y)))
                + ((bfhi(v4.y) + bfhi(v5.y)) + (bfhi(v6.y) + bfhi(v7.y)));
        acc[4] += ((bflo(v0.z) + bflo(v1.z)) + (bflo(v2.z) + bflo(v3.z)))
                + ((bflo(v4.z) + bflo(v5.z)) + (bflo(v6.z) + bflo(v7.z)));
        acc[5] += ((bfhi(v0.z) + bfhi(v1.z)) + (bfhi(v2.z) + bfhi(v3.z)))
                + ((bfhi(v4.z) + bfhi(v5.z)) + (bfhi(v6.z) + bfhi(v7.z)));
        acc[6] += ((bflo(v0.w) + bflo(v1.w)) + (bflo(v2.w) + bflo(v3.w)))
                + ((bflo(v4.w) + bflo(v5.w)) + (bflo(v6.w) + bflo(v7.w)));
        acc[7] += ((bfhi(v0.w) + bfhi(v1.w)) + (bfhi(v2.w) + bfhi(v3.w)))
                + ((bfhi(v4.w) + bfhi(v5.w)) + (bfhi(v6.w) + bfhi(v7.w)));
    }
    for (; i < mydeg; ++i) {
        int s = csr_src[myoff + i];
        uint4 v = ((const uint4*)(h2wd + (size_t)s * 8))[q];
        acc[0] += bflo(v.x); acc[1] += bfhi(v.x);
        acc[2] += bflo(v.y); acc[3] += bfhi(v.y);
        acc[4] += bflo(v.z); acc[5] += bfhi(v.z);
        acc[6] += bflo(v.w); acc[7] += bfhi(v.w);
    }
    // combine edge-halves (linear, safe before relu)
#pragma unroll
    for (int j = 0; j < 8; ++j) acc[j] += __shfl_xor(acc[j], 2, 64);
    // fused head: out[node] = relu(acc*dv + b2) . Wf + bf  (pair-split dot)
    float dv = dinv[node];
    const float* bq = bs_ + q * 8;
    const float* wq = wf_ + q * 8;
    float part = 0.f;
#pragma unroll
    for (int k = 0; k < 8; ++k)
        part += fmaxf(acc[k] * dv + bq[k], 0.f) * wq[k];
    part += __shfl_xor(part, 1, 64);  // combine the slice halves
    if ((t & 3) == 0) out[node] = part + bfv;
}

extern "C" void kernel_launch(void* const* d_in, const int* in_sizes, int n_in,
                              void* d_out, int out_size, void* d_ws, size_t ws_size,
                              hipStream_t stream) {
    const float* x  = (const float*)d_in[0];
    const int*   ei = (const int*)d_in[1];
    const float* W1 = (const float*)d_in[2];
    const float* b1 = (const float*)d_in[3];
    const float* W2 = (const float*)d_in[4];
    const float* b2 = (const float*)d_in[5];
    const float* Wf = (const float*)d_in[6];
    const float* bf = (const float*)d_in[7];

    int N = in_sizes[0] / 128;
    int E = in_sizes[1] / 2;
    const int* src = ei;       // edge_index[0]
    const int* dst = ei + E;   // edge_index[1]
    int NPB = (N + NBUCK - 1) / NBUCK;  // 196 for N=100k

    // Workspace layout
    size_t Np = ((size_t)N + 3) & ~(size_t)3;
    size_t Ep = ((size_t)E + 3) & ~(size_t)3;
    int* wsI      = (int*)d_ws;
    int* counts   = wsI;                 // Np
    int* offs     = counts + Np;         // Np
    int* bcur     = offs + Np;           // NBUCK
    int* csr_src  = bcur + NBUCK;        // Ep
    float* dinv   = (float*)(csr_src + Ep);      // Np
    unsigned* xwd = (unsigned*)(dinv + Np);      // 16*Np u32 (bf16, 64B rows)
    unsigned* staging = xwd + 16 * Np;           // NBUCK*BCAP u32 = 16.8 MB
    // h2wd (8*N u32 = 3.2 MB) aliases staging: staging written by binA2,
    // read last by buildB; h2wd first written by aggF (later). No overlap.
    unsigned* h2wd = staging;
    float* out    = (float*)d_out;

    int nbC  = (E + CHUNK - 1) / CHUNK;  // 782
    int nbG1 = (N + 127) / 128;          // 782 (2 nodes/thread)
    int nbA32 = (N + 31) / 32;   // 32 nodes/block (8 lanes/node)
    int nbA16 = (N + 63) / 64;   // 64 nodes/block (4 lanes/node)

    hipMemsetAsync(bcur, 0, NBUCK * sizeof(int), stream);
    binA2_kernel<<<nbC, 512, 0, stream>>>(src, dst, bcur, staging, E, NPB);
    buildB_kernel<<<NBUCK, 512, 0, stream>>>(bcur, staging, offs, counts,
                                             dinv, csr_src, N, NPB);
    gemm1_kernel<<<nbG1, 256, 0, stream>>>(x, W1, dinv, xwd, N);
    aggF_kernel<<<nbA32, 256, 0, stream>>>(offs, counts, csr_src, dinv, xwd,
                                           b1, W2, h2wd, N);
    aggS16f_kernel<<<nbA16, 256, 0, stream>>>(offs, counts, csr_src, dinv, h2wd,
                                              b2, Wf, bf, out, N);
}

// Round 12
// 236.133 us; speedup vs baseline: 2.0889x; 1.0398x over previous
//
#include <hip/hip_runtime.h>

// GCN forward via two-level CSR build + gather aggregation.
// Lessons ledger:
//   R4/R9:  atomic float aggregation (global) loses 5-10x to register gather.
//   R15:    ...and LDS float atomics lose too (591us). Register accum only.
//   R17:    scattered 4B global writes forbidden (partial-line write
//           amplification across 8 non-coherent L2s -> 300us scatter).
//   R13/18/20: gather per-lane MLP exhausted at x8 batches (51->45us).
//   R22:    top-5 visibility threshold = 41.5us harness fill; ~4us/dispatch.
//   R23/24: cooperative fused build intrinsically ~270us. Abandoned.
//   R26:    TRUE accounting of 244.7us: aggF 45 + aggS16f 27 + build trio 34
//           + FIXED ~139 (harness fill + graph/dispatch overhead).
//   R28 (R11 A/B): wave-splitting edge lists pays ONLY when under-waved with
//           a cheap epilogue: aggF 8-lane REGRESSED 45->53 (fixed cost x2,
//           epilogue dup, short half-lists); aggS16f 4-lane GAINED 27->~20.
//   R29 (this round): compose best-of-both: aggF = R6 4-lane form (45.1,
//           verified), aggS16f = R11 4-lane half-split form (~20). If total
//           lands 236-240 with kernels at verified floors, budget exhausted.
// Pipeline (6 dispatches):
//   memset(bcur)
//   binA2: per-block LDS radix partition -> 512 dst-range buckets.
//   buildB: inline bucket-base scan + per-bucket hist/scan -> CSR + dinv.
//   gemm1: xwd = (x@W1)*dinv, bf16 64B rows, 4 thr/node x 2 nodes/thr.
//   aggF: layer-1 gather (4 lanes/node, x8 pipelined) + fused gemm2 -> h2wd.
//   aggS16f: layer-2 gather (4 lanes/node: 2 slices x 2 halves) + head.

#define TPB 256
#define NBUCK 512
#define BCAP 8192    // bucket capacity; mean ~6272, sd ~79 -> 24 sigma margin
#define CHUNK 4096   // edges per binA2 block -> 782 blocks

__device__ __forceinline__ unsigned f2bf(float f) {  // RNE fp32->bf16
    unsigned u = __float_as_uint(f);
    return (u + 0x7FFFu + ((u >> 16) & 1u)) >> 16;
}
__device__ __forceinline__ float bflo(unsigned u) { return __uint_as_float(u << 16); }
__device__ __forceinline__ float bfhi(unsigned u) { return __uint_as_float(u & 0xFFFF0000u); }

// Exclusive scan over 512 values (one per thread) using wave shfl scans.
__device__ __forceinline__ int excl_scan_512(int v, int* wsum, int tid) {
    int lane = tid & 63, wv = tid >> 6;
    int x = v;
#pragma unroll
    for (int d = 1; d < 64; d <<= 1) {
        int y = __shfl_up(x, d, 64);
        if (lane >= d) x += y;
    }
    if (lane == 63) wsum[wv] = x;          // inclusive wave sum
    __syncthreads();
    if (tid < 64) {
        int s = (lane < 8) ? wsum[lane] : 0;
#pragma unroll
        for (int d = 1; d < 8; d <<= 1) {
            int y = __shfl_up(s, d, 64);
            if (lane >= d) s += y;
        }
        if (lane < 8) wsum[lane] = s;      // inclusive across waves
    }
    __syncthreads();
    int base = (wv > 0) ? wsum[wv - 1] : 0;
    return base + x - v;                   // exclusive prefix
}

// Phase A: block-local radix partition, bulk append to global staging.
__global__ __launch_bounds__(512) void binA2_kernel(
        const int* __restrict__ src, const int* __restrict__ dst,
        int* __restrict__ bcur, unsigned* __restrict__ staging, int E, int NPB) {
    __shared__ unsigned packed[CHUNK];         // 16 KB
    __shared__ unsigned short buckb[CHUNK];    // 8 KB
    __shared__ int hist[NBUCK];                // 2 KB each
    __shared__ int lstart[NBUCK];
    __shared__ int lcur[NBUCK];
    __shared__ int gbase[NBUCK];
    __shared__ int wsum[8];
    int tid = threadIdx.x;
    int start = blockIdx.x * CHUNK;
    int sz = min(CHUNK, E - start);

    unsigned dreg[8], sreg[8];
    hist[tid] = 0;
#pragma unroll
    for (int c = 0; c < 8; ++c) {              // compile-time idx -> VGPRs
        int i = tid + c * 512;
        if (i < sz) {
            dreg[c] = (unsigned)dst[start + i];
            sreg[c] = (unsigned)src[start + i];
        } else {
            dreg[c] = 0xFFFFFFFFu;             // sentinel (real d < N)
        }
    }
    __syncthreads();
#pragma unroll
    for (int c = 0; c < 8; ++c)
        if (dreg[c] != 0xFFFFFFFFu) atomicAdd(&hist[dreg[c] / (unsigned)NPB], 1);
    __syncthreads();
    int v = hist[tid];
    int excl = excl_scan_512(v, wsum, tid);
    lstart[tid] = excl;
    lcur[tid] = 0;
    gbase[tid] = atomicAdd(&bcur[tid], v);     // one reservation per (block,bucket)
    __syncthreads();
#pragma unroll
    for (int c = 0; c < 8; ++c) {
        if (dreg[c] == 0xFFFFFFFFu) continue;
        unsigned d = dreg[c];
        unsigned b = d / (unsigned)NPB;
        unsigned loc = d - b * (unsigned)NPB;
        int pos = atomicAdd(&lcur[b], 1);
        int si = lstart[b] + pos;
        packed[si] = (loc << 20) | sreg[c];    // loc<=195 (12b), src<2^17
        buckb[si] = (unsigned short)b;
    }
    __syncthreads();
    for (int i = tid; i < sz; i += 512) {      // bucket-contiguous bulk write
        unsigned b = buckb[i];
        int dsti = gbase[b] + (i - lstart[b]);
        if (dsti < BCAP)
            staging[(size_t)b * BCAP + dsti] = packed[i];
    }
}

// Phase B: one block per bucket; inline bucket-base scan; hist + wave-scan
// -> counts/offs/dinv + CSR placement.
__global__ __launch_bounds__(512) void buildB_kernel(
        const int* __restrict__ bcur, const unsigned* __restrict__ staging,
        int* __restrict__ offs, int* __restrict__ counts,
        float* __restrict__ dinv, int* __restrict__ csr_src,
        int N, int NPB) {
    __shared__ int hist[512];
    __shared__ int cur[512];
    __shared__ int wsum[8];
    __shared__ int base_sh;
    int b = blockIdx.x;
    int tid = threadIdx.x;
    // inline bbase: exclusive prefix of clamped bucket sizes; keep entry b
    int myv = min(bcur[tid], BCAP);
    int bexcl = excl_scan_512(myv, wsum, tid);
    if (tid == b) base_sh = bexcl;
    int sz = min(bcur[b], BCAP);
    int n0 = b * NPB;
    int nn = min(NPB, N - n0);
    const unsigned* se = staging + (size_t)b * BCAP;

    unsigned preg[16];                         // BCAP/512 = 16 covers any sz
    hist[tid] = 0;
#pragma unroll
    for (int c = 0; c < 16; ++c) {
        int i = tid + c * 512;
        preg[c] = (i < sz) ? se[i] : 0xFFFFFFFFu;
    }
    __syncthreads();
    int base = base_sh;
#pragma unroll
    for (int c = 0; c < 16; ++c)
        if (preg[c] != 0xFFFFFFFFu) atomicAdd(&hist[preg[c] >> 20], 1);
    __syncthreads();
    int h = hist[tid];
    int excl = excl_scan_512(h, wsum, tid);
    cur[tid] = excl;
    if (tid < nn) {
        int node = n0 + tid;
        offs[node] = base + excl;
        counts[node] = h;
        dinv[node] = rsqrtf((float)(h + 1));   // +1 self-loop
    }
    __syncthreads();
#pragma unroll
    for (int c = 0; c < 16; ++c) {
        unsigned p = preg[c];
        if (p == 0xFFFFFFFFu) continue;
        int pos = atomicAdd(&cur[p >> 20], 1);
        csr_src[base + pos] = (int)(p & 0xFFFFFu);
    }
}

// xwd(bf16) = (x @ W1) * dinv[node].  4 threads/node x 8 cols x 2 nodes/thr.
__global__ __launch_bounds__(256) void gemm1_kernel(
        const float* __restrict__ x, const float* __restrict__ W1,
        const float* __restrict__ dinv, unsigned* __restrict__ xwd, int N) {
    __shared__ float ws_[128 * 32];
    for (int i = threadIdx.x; i < 128 * 32; i += 256) ws_[i] = W1[i];
    __syncthreads();
    int t = threadIdx.x;
    int jq = (t & 3) * 8;  // 8 output cols
    int n0 = blockIdx.x * 128 + (t >> 2) * 2;
    if (n0 >= N) return;
    int nc0 = min(n0 + 0, N - 1);
    int nc1 = min(n0 + 1, N - 1);
    const float4* xr0 = (const float4*)(x + (size_t)nc0 * 128);
    const float4* xr1 = (const float4*)(x + (size_t)nc1 * 128);
    float acc[2][8];
#pragma unroll
    for (int n = 0; n < 2; ++n)
#pragma unroll
        for (int j = 0; j < 8; ++j) acc[n][j] = 0.0f;
#pragma unroll 2
    for (int k4 = 0; k4 < 32; ++k4) {
        const float* wb = ws_ + (k4 * 4) * 32 + jq;
        float4 a0 = *(const float4*)(wb);
        float4 a1 = *(const float4*)(wb + 4);
        float4 b0 = *(const float4*)(wb + 32);
        float4 b1v = *(const float4*)(wb + 36);
        float4 c0 = *(const float4*)(wb + 64);
        float4 c1 = *(const float4*)(wb + 68);
        float4 d0 = *(const float4*)(wb + 96);
        float4 d1 = *(const float4*)(wb + 100);
        float4 xv0 = xr0[k4];
        float4 xv1 = xr1[k4];
#pragma unroll
        for (int n = 0; n < 2; ++n) {
            float4 xv = (n == 0) ? xv0 : xv1;
            acc[n][0] += xv.x * a0.x + xv.y * b0.x + xv.z * c0.x + xv.w * d0.x;
            acc[n][1] += xv.x * a0.y + xv.y * b0.y + xv.z * c0.y + xv.w * d0.y;
            acc[n][2] += xv.x * a0.z + xv.y * b0.z + xv.z * c0.z + xv.w * d0.z;
            acc[n][3] += xv.x * a0.w + xv.y * b0.w + xv.z * c0.w + xv.w * d0.w;
            acc[n][4] += xv.x * a1.x + xv.y * b1v.x + xv.z * c1.x + xv.w * d1.x;
            acc[n][5] += xv.x * a1.y + xv.y * b1v.y + xv.z * c1.y + xv.w * d1.y;
            acc[n][6] += xv.x * a1.z + xv.y * b1v.z + xv.z * c1.z + xv.w * d1.z;
            acc[n][7] += xv.x * a1.w + xv.y * b1v.w + xv.z * c1.w + xv.w * d1.w;
        }
    }
#pragma unroll
    for (int n = 0; n < 2; ++n) {
        int node = n0 + n;
        if (node >= N) break;
        float d = dinv[node];
        unsigned pk0 = f2bf(acc[n][0] * d) | (f2bf(acc[n][1] * d) << 16);
        unsigned pk1 = f2bf(acc[n][2] * d) | (f2bf(acc[n][3] * d) << 16);
        unsigned pk2 = f2bf(acc[n][4] * d) | (f2bf(acc[n][5] * d) << 16);
        unsigned pk3 = f2bf(acc[n][6] * d) | (f2bf(acc[n][7] * d) << 16);
        ((uint4*)(xwd + (size_t)node * 16))[t & 3] = make_uint4(pk0, pk1, pk2, pk3);
    }
}

// Layer-1 aggregate FUSED with gemm2: 4 lanes/node, x8 gather batches with
// next-batch index prefetch (R6 form, 45.1us verified), register accum, then
// h2wd = (relu(agg*dv + b1) @ W2) * dv via LDS W2 + 12-shuffle butterfly.
__global__ __launch_bounds__(256) void aggF_kernel(
        const int* __restrict__ offs, const int* __restrict__ counts,
        const int* __restrict__ csr_src, const float* __restrict__ dinv,
        const unsigned* __restrict__ xwd, const float* __restrict__ b1,
        const float* __restrict__ W2, unsigned* __restrict__ h2wd, int N) {
    __shared__ float ws2[32 * 16];
    for (int i = threadIdx.x; i < 512; i += 256) ws2[i] = W2[i];
    __syncthreads();
    int t = threadIdx.x;
    int q = t & 3;                       // 16B slice
    int node = blockIdx.x * 64 + (t >> 2);
    if (node >= N) return;
    int off = offs[node];
    int deg = counts[node];
    float acc[8];
    {
        uint4 v = ((const uint4*)(xwd + (size_t)node * 16))[q];  // self term
        acc[0] = bflo(v.x); acc[1] = bfhi(v.x);
        acc[2] = bflo(v.y); acc[3] = bfhi(v.y);
        acc[4] = bflo(v.z); acc[5] = bfhi(v.z);
        acc[6] = bflo(v.w); acc[7] = bfhi(v.w);
    }
    int deg8 = deg & ~7;
    int idx[8];
    if (deg8 > 0) {
#pragma unroll
        for (int c = 0; c < 8; ++c) idx[c] = csr_src[off + c];
    }
    int i = 0;
    while (i < deg8) {
        uint4 v0 = ((const uint4*)(xwd + (size_t)idx[0] * 16))[q];
        uint4 v1 = ((const uint4*)(xwd + (size_t)idx[1] * 16))[q];
        uint4 v2 = ((const uint4*)(xwd + (size_t)idx[2] * 16))[q];
        uint4 v3 = ((const uint4*)(xwd + (size_t)idx[3] * 16))[q];
        uint4 v4 = ((const uint4*)(xwd + (size_t)idx[4] * 16))[q];
        uint4 v5 = ((const uint4*)(xwd + (size_t)idx[5] * 16))[q];
        uint4 v6 = ((const uint4*)(xwd + (size_t)idx[6] * 16))[q];
        uint4 v7 = ((const uint4*)(xwd + (size_t)idx[7] * 16))[q];
        i += 8;
        if (i < deg8) {                  // prefetch next batch's indices
#pragma unroll
            for (int c = 0; c < 8; ++c) idx[c] = csr_src[off + i + c];
        }
        acc[0] += ((bflo(v0.x) + bflo(v1.x)) + (bflo(v2.x) + bflo(v3.x)))
                + ((bflo(v4.x) + bflo(v5.x)) + (bflo(v6.x) + bflo(v7.x)));
        acc[1] += ((bfhi(v0.x) + bfhi(v1.x)) + (bfhi(v2.x) + bfhi(v3.x)))
                + ((bfhi(v4.x) + bfhi(v5.x)) + (bfhi(v6.x) + bfhi(v7.x)));
        acc[2] += ((bflo(v0.y) + bflo(v1.y)) + (bflo(v2.y) + bflo(v3.y)))
                + ((bflo(v4.y) + bflo(v5.y)) + (bflo(v6.y) + bflo(v7.y)));
        acc[3] += ((bfhi(v0.y) + bfhi(v1.y)) + (bfhi(v2.y) + bfhi(v3.y)))
                + ((bfhi(v4.y) + bfhi(v5.y)) + (bfhi(v6.y) + bfhi(v7.y)));
        acc[4] += ((bflo(v0.z) + bflo(v1.z)) + (bflo(v2.z) + bflo(v3.z)))
                + ((bflo(v4.z) + bflo(v5.z)) + (bflo(v6.z) + bflo(v7.z)));
        acc[5] += ((bfhi(v0.z) + bfhi(v1.z)) + (bfhi(v2.z) + bfhi(v3.z)))
                + ((bfhi(v4.z) + bfhi(v5.z)) + (bfhi(v6.z) + bfhi(v7.z)));
        acc[6] += ((bflo(v0.w) + bflo(v1.w)) + (bflo(v2.w) + bflo(v3.w)))
                + ((bflo(v4.w) + bflo(v5.w)) + (bflo(v6.w) + bflo(v7.w)));
        acc[7] += ((bfhi(v0.w) + bfhi(v1.w)) + (bfhi(v2.w) + bfhi(v3.w)))
                + ((bfhi(v4.w) + bfhi(v5.w)) + (bfhi(v6.w) + bfhi(v7.w)));
    }
    for (; i < deg; ++i) {
        int s = csr_src[off + i];
        uint4 v = ((const uint4*)(xwd + (size_t)s * 16))[q];
        acc[0] += bflo(v.x); acc[1] += bfhi(v.x);
        acc[2] += bflo(v.y); acc[3] += bfhi(v.y);
        acc[4] += bflo(v.z); acc[5] += bfhi(v.z);
        acc[6] += bflo(v.w); acc[7] += bfhi(v.w);
    }
    float dv = dinv[node];
    // fused gemm2: lane q owns k = q*8..q*8+7 of the 32-dim hidden vector
    float part[16];
#pragma unroll
    for (int j = 0; j < 16; ++j) part[j] = 0.0f;
    const float* bq = b1 + q * 8;
#pragma unroll
    for (int k = 0; k < 8; ++k) {
        float h = fmaxf(acc[k] * dv + bq[k], 0.0f);
        const float* wr = ws2 + (q * 8 + k) * 16;
        float4 w0 = *(const float4*)(wr);
        float4 w1 = *(const float4*)(wr + 4);
        float4 w2 = *(const float4*)(wr + 8);
        float4 w3 = *(const float4*)(wr + 12);
        part[0]  += h * w0.x; part[1]  += h * w0.y; part[2]  += h * w0.z; part[3]  += h * w0.w;
        part[4]  += h * w1.x; part[5]  += h * w1.y; part[6]  += h * w1.z; part[7]  += h * w1.w;
        part[8]  += h * w2.x; part[9]  += h * w2.y; part[10] += h * w2.z; part[11] += h * w2.w;
        part[12] += h * w3.x; part[13] += h * w3.y; part[14] += h * w3.z; part[15] += h * w3.w;
    }
    // half-exchange butterfly over the quad: 8 + 4 shfl total.
    float p8[8];
#pragma unroll
    for (int j = 0; j < 8; ++j) {
        float send = (q & 1) ? part[j] : part[j + 8];
        float keep = (q & 1) ? part[j + 8] : part[j];
        p8[j] = keep + __shfl_xor(send, 1, 64);
    }
    float p4[4];
#pragma unroll
    for (int j = 0; j < 4; ++j) {
        float send = (q & 2) ? p8[j] : p8[j + 4];
        float keep = (q & 2) ? p8[j + 4] : p8[j];
        p4[j] = keep + __shfl_xor(send, 2, 64);
    }
    unsigned pk0 = f2bf(p4[0] * dv) | (f2bf(p4[1] * dv) << 16);
    unsigned pk1 = f2bf(p4[2] * dv) | (f2bf(p4[3] * dv) << 16);
    int slot = ((q & 1) << 1) | ((q >> 1) & 1);   // col base /4: q0->0 q1->2 q2->1 q3->3
    ((uint2*)(h2wd + (size_t)node * 8))[slot] = make_uint2(pk0, pk1);
}

// Layer-2 aggregate + fused head.  R11 form (~20us): 4 lanes/node = 2 slices
// (q=t&1) x 2 edge-halves (h=bit1); halves combined via shfl_xor(.,2).
__global__ __launch_bounds__(256) void aggS16f_kernel(
        const int* __restrict__ offs, const int* __restrict__ counts,
        const int* __restrict__ csr_src, const float* __restrict__ dinv,
        const unsigned* __restrict__ h2wd,
        const float* __restrict__ b2, const float* __restrict__ Wf,
        const float* __restrict__ bf, float* __restrict__ out, int N) {
    __shared__ float bs_[16];
    __shared__ float wf_[16];
    __shared__ float bfv;
    int t = threadIdx.x;
    if (t < 16) { bs_[t] = b2[t]; wf_[t] = Wf[t]; }
    if (t == 0) bfv = bf[0];
    __syncthreads();
    int q = t & 1;                        // 16B slice (8 feats)
    int h = (t >> 1) & 1;                 // edge-half
    int node = blockIdx.x * 64 + (t >> 2);
    if (node >= N) return;
    int off = offs[node];
    int deg = counts[node];
    int d0 = (deg + 1) >> 1;
    int mydeg = h ? (deg - d0) : d0;
    int myoff = off + (h ? d0 : 0);
    float acc[8];
    if (h == 0) {                         // self term once
        uint4 v = ((const uint4*)(h2wd + (size_t)node * 8))[q];
        acc[0] = bflo(v.x); acc[1] = bfhi(v.x);
        acc[2] = bflo(v.y); acc[3] = bfhi(v.y);
        acc[4] = bflo(v.z); acc[5] = bfhi(v.z);
        acc[6] = bflo(v.w); acc[7] = bfhi(v.w);
    } else {
#pragma unroll
        for (int j = 0; j < 8; ++j) acc[j] = 0.0f;
    }
    int deg8 = mydeg & ~7;
    int idx[8];
    if (deg8 > 0) {
#pragma unroll
        for (int c = 0; c < 8; ++c) idx[c] = csr_src[myoff + c];
    }
    int i = 0;
    while (i < deg8) {
        uint4 v0 = ((const uint4*)(h2wd + (size_t)idx[0] * 8))[q];
        uint4 v1 = ((const uint4*)(h2wd + (size_t)idx[1] * 8))[q];
        uint4 v2 = ((const uint4*)(h2wd + (size_t)idx[2] * 8))[q];
        uint4 v3 = ((const uint4*)(h2wd + (size_t)idx[3] * 8))[q];
        uint4 v4 = ((const uint4*)(h2wd + (size_t)idx[4] * 8))[q];
        uint4 v5 = ((const uint4*)(h2wd + (size_t)idx[5] * 8))[q];
        uint4 v6 = ((const uint4*)(h2wd + (size_t)idx[6] * 8))[q];
        uint4 v7 = ((const uint4*)(h2wd + (size_t)idx[7] * 8))[q];
        i += 8;
        if (i < deg8) {
#pragma unroll
            for (int c = 0; c < 8; ++c) idx[c] = csr_src[myoff + i + c];
        }
        acc[0] += ((bflo(v0.x) + bflo(v1.x)) + (bflo(v2.x) + bflo(v3.x)))
                + ((bflo(v4.x) + bflo(v5.x)) + (bflo(v6.x) + bflo(v7.x)));
        acc[1] += ((bfhi(v0.x) + bfhi(v1.x)) + (bfhi(v2.x) + bfhi(v3.x)))
                + ((bfhi(v4.x) + bfhi(v5.x)) + (bfhi(v6.x) + bfhi(v7.x)));
        acc[2] += ((bflo(v0.y) + bflo(v1.y)) + (bflo(v2.y) + bflo(v3.y)))
                + ((bflo(v4.y) + bflo(v5.y)) + (bflo(v6.y) + bflo(v7.y)));
        acc[3] += ((bfhi(v0.y) + bfhi(v1.y)) + (bfhi(v2.y) + bfhi(v3.y)))
                + ((bfhi(v4.y) + bfhi(v5.y)) + (bfhi(v6.y) + bfhi(v7.y)));
        acc[4] += ((bflo(v0.z) + bflo(v1.z)) + (bflo(v2.z) + bflo(v3.z)))
                + ((bflo(v4.z) + bflo(v5.z)) + (bflo(v6.z) + bflo(v7.z)));
        acc[5] += ((bfhi(v0.z) + bfhi(v1.z)) + (bfhi(v2.z) + bfhi(v3.z)))
                + ((bfhi(v4.z) + bfhi(v5.z)) + (bfhi(v6.z) + bfhi(v7.z)));
        acc[6] += ((bflo(v0.w) + bflo(v1.w)) + (bflo(v2.w) + bflo(v3.w)))
                + ((bflo(v4.w) + bflo(v5.w)) + (bflo(v6.w) + bflo(v7.w)));
        acc[7] += ((bfhi(v0.w) + bfhi(v1.w)) + (bfhi(v2.w) + bfhi(v3.w)))
                + ((bfhi(v4.w) + bfhi(v5.w)) + (bfhi(v6.w) + bfhi(v7.w)));
    }
    for (; i < mydeg; ++i) {
        int s = csr_src[myoff + i];
        uint4 v = ((const uint4*)(h2wd + (size_t)s * 8))[q];
        acc[0] += bflo(v.x); acc[1] += bfhi(v.x);
        acc[2] += bflo(v.y); acc[3] += bfhi(v.y);
        acc[4] += bflo(v.z); acc[5] += bfhi(v.z);
        acc[6] += bflo(v.w); acc[7] += bfhi(v.w);
    }
    // combine edge-halves (linear, safe before relu)
#pragma unroll
    for (int j = 0; j < 8; ++j) acc[j] += __shfl_xor(acc[j], 2, 64);
    // fused head: out[node] = relu(acc*dv + b2) . Wf + bf  (pair-split dot)
    float dv = dinv[node];
    const float* bq = bs_ + q * 8;
    const float* wq = wf_ + q * 8;
    float part = 0.f;
#pragma unroll
    for (int k = 0; k < 8; ++k)
        part += fmaxf(acc[k] * dv + bq[k], 0.f) * wq[k];
    part += __shfl_xor(part, 1, 64);  // combine the slice halves
    if ((t & 3) == 0) out[node] = part + bfv;
}

extern "C" void kernel_launch(void* const* d_in, const int* in_sizes, int n_in,
                              void* d_out, int out_size, void* d_ws, size_t ws_size,
                              hipStream_t stream) {
    const float* x  = (const float*)d_in[0];
    const int*   ei = (const int*)d_in[1];
    const float* W1 = (const float*)d_in[2];
    const float* b1 = (const float*)d_in[3];
    const float* W2 = (const float*)d_in[4];
    const float* b2 = (const float*)d_in[5];
    const float* Wf = (const float*)d_in[6];
    const float* bf = (const float*)d_in[7];

    int N = in_sizes[0] / 128;
    int E = in_sizes[1] / 2;
    const int* src = ei;       // edge_index[0]
    const int* dst = ei + E;   // edge_index[1]
    int NPB = (N + NBUCK - 1) / NBUCK;  // 196 for N=100k

    // Workspace layout
    size_t Np = ((size_t)N + 3) & ~(size_t)3;
    size_t Ep = ((size_t)E + 3) & ~(size_t)3;
    int* wsI      = (int*)d_ws;
    int* counts   = wsI;                 // Np
    int* offs     = counts + Np;         // Np
    int* bcur     = offs + Np;           // NBUCK
    int* csr_src  = bcur + NBUCK;        // Ep
    float* dinv   = (float*)(csr_src + Ep);      // Np
    unsigned* xwd = (unsigned*)(dinv + Np);      // 16*Np u32 (bf16, 64B rows)
    unsigned* staging = xwd + 16 * Np;           // NBUCK*BCAP u32 = 16.8 MB
    // h2wd (8*N u32 = 3.2 MB) aliases staging: staging written by binA2,
    // read last by buildB; h2wd first written by aggF (later). No overlap.
    unsigned* h2wd = staging;
    float* out    = (float*)d_out;

    int nbC  = (E + CHUNK - 1) / CHUNK;  // 782
    int nbG1 = (N + 127) / 128;          // 782 (2 nodes/thread)
    int nbA32 = (N + 63) / 64;   // 64 nodes/block (4 lanes/node)
    int nbA16 = (N + 63) / 64;   // 64 nodes/block (4 lanes/node, half-split)

    hipMemsetAsync(bcur, 0, NBUCK * sizeof(int), stream);
    binA2_kernel<<<nbC, 512, 0, stream>>>(src, dst, bcur, staging, E, NPB);
    buildB_kernel<<<NBUCK, 512, 0, stream>>>(bcur, staging, offs, counts,
                                             dinv, csr_src, N, NPB);
    gemm1_kernel<<<nbG1, 256, 0, stream>>>(x, W1, dinv, xwd, N);
    aggF_kernel<<<nbA32, 256, 0, stream>>>(offs, counts, csr_src, dinv, xwd,
                                           b1, W2, h2wd, N);
    aggS16f_kernel<<<nbA16, 256, 0, stream>>>(offs, counts, csr_src, dinv, h2wd,
                                              b2, Wf, bf, out, N);
}